// Round 6
// baseline (17002.432 us; speedup 1.0000x reference)
//
#include <hip/hip_runtime.h>

typedef short short8 __attribute__((ext_vector_type(8)));
typedef float f32x4 __attribute__((ext_vector_type(4)));
typedef unsigned int u32x4 __attribute__((ext_vector_type(4)));
typedef unsigned long long ull;

#define NB 64
#define NT 1024
#define NI 128
#define NH 512

// ws layout (bytes):
//   0        : M      512KB  combined recurrent matrix, bf16 [512][512]
//   524288   : WiT    128KB
//   655360   : X      128KB  h-half exchange: ((g*2+role)*2+parity)*8KB + tid*32
//   786432   : flags  4KB    ((g*2+role)*4+w)*64B, monotone seq
//   790528   : xcc    64B    per-bid xcc-id table
//   1048576  : xp     64MB   [t][b][256] f32
#define WS_X     655360
#define WS_FLAGS 786432
#define WS_XCC   790528
#define WS_XP    1048576

#define SWZ(m) ((unsigned)(((m) & 7) << 3))

__device__ __forceinline__ unsigned short f2bf(float f) {
  union { float f; unsigned u; } v; v.f = f;
  unsigned u = v.u;
  return (unsigned short)((u + 0x7FFFu + ((u >> 16) & 1u)) >> 16);
}

union V128 { short8 s; u32x4 u; };

__device__ __forceinline__ f32x4 mfma16(short8 a, short8 b, f32x4 c) {
  return __builtin_amdgcn_mfma_f32_16x16x32_bf16(a, b, c, 0, 0, 0);
}

// Build combined recurrent matrix M[o][k] (512x512 bf16), scales folded in.
// Also zeroes flags/xcc (stream-ordered before rnn_k: graph-replay safe).
__global__ __launch_bounds__(256) void buildM_k(
    const float* __restrict__ W11, const float* __restrict__ W22,
    const float* __restrict__ W12, const float* __restrict__ W21,
    unsigned short* __restrict__ M, unsigned* __restrict__ ctrl) {
  if (blockIdx.x == 0) {
    #pragma unroll
    for (int i = 0; i < 8; i++) ctrl[threadIdx.x + 256 * i] = 0;  // 8KB
  }
  int idx = blockIdx.x * 256 + threadIdx.x;  // 262144 total
  int o = idx >> 9, k = idx & 511;
  const float A1f = (float)(16.67 / 100.0);
  float v;
  if (o < 256) {
    v = (k < 256) ? A1f * W11[(o << 8) + k]
                  : A1f * 0.5f * W21[(o << 8) + (k - 256)];
  } else {
    int o2 = o - 256;
    v = (k < 256) ? A1f * 0.5f * W12[(o2 << 8) + k]
                  : A1f * W22[(o2 << 8) + (k - 256)];
  }
  M[idx] = f2bf(v);
}

__global__ __launch_bounds__(256) void buildWiT_k(const float* __restrict__ Wi,
                                                  float* __restrict__ WiT) {
  int idx = blockIdx.x * 256 + threadIdx.x;  // 32768 = 128*256, WiT[k][o]
  int k = idx >> 8, o = idx & 255;
  WiT[idx] = Wi[o * 128 + k];
}

// xp'[t][b][o] = A1 * (sum_i x[b][t][i]*Wi[o][i] + bi[o]), f32, layout [t][b][o].
__global__ __launch_bounds__(256) void xproj_k(
    const float* __restrict__ x, const float* __restrict__ WiT,
    const float* __restrict__ bi, float* __restrict__ xp) {
  __shared__ float xs[128 * 68];
  int tid = threadIdx.x;
  int wv = tid >> 6;
  int c = tid & 63;
  long Rbase = (long)blockIdx.x * 64;
  const float* xg = x + Rbase * 128;
  #pragma unroll
  for (int i = 0; i < 32; i++) {
    int idx = tid + 256 * i;
    int r = idx >> 7, k = idx & 127;
    xs[k * 68 + r] = xg[idx];
  }
  __syncthreads();
  float acc[4][16];
  #pragma unroll
  for (int a = 0; a < 4; a++)
    #pragma unroll
    for (int b = 0; b < 16; b++) acc[a][b] = 0.f;
  for (int k = 0; k < 128; k++) {
    f32x4 w4 = *(const f32x4*)(WiT + k * 256 + 4 * c);
    const float* xr = &xs[k * 68 + 16 * wv];
    #pragma unroll
    for (int rr = 0; rr < 4; rr++) {
      f32x4 xv = *(const f32x4*)(xr + 4 * rr);
      #pragma unroll
      for (int cc = 0; cc < 4; cc++) {
        #pragma unroll
        for (int u = 0; u < 4; u++)
          acc[cc][4 * rr + u] = fmaf(w4[cc], xv[u], acc[cc][4 * rr + u]);
      }
    }
  }
  f32x4 bv = *(const f32x4*)(bi + 4 * c);
  const float A1f = (float)(16.67 / 100.0);
  #pragma unroll
  for (int rr = 0; rr < 16; rr++) {
    long R = Rbase + 16 * wv + rr;
    int b = (int)(R >> 10), t = (int)(R & 1023);
    f32x4 o;
    #pragma unroll
    for (int cc = 0; cc < 4; cc++) o[cc] = A1f * (acc[cc][rr] + bv[cc]);
    *(f32x4*)(xp + ((long)(t * 64 + b) << 8) + 4 * c) = o;
  }
}

// Recurrent kernel: output-split pairs, AGPR-pinned weights, BUILTIN MFMA
// (compiler-managed MFMA hazards — the R5 inline-asm MFMA lacked wait-states).
// grid 16; active bids {0..3}=role0 (cols 0..255), {8..11}=role1 (cols 256..511);
// pair (g, g+8) lands on one XCD under bid%8 round-robin (runtime-verified).
// 256 threads = 4 waves (1/SIMD -> 512-reg budget). Wave w owns 64 cols over
// full K=512: weights = 64 quads = 256 AGPRs/thread + ~130 VGPR working.
// Step: recv(partner h; load latency hidden by phase A) | A: own-k MFMA |
// scatter partner h -> LDS | barrier | C: partner-k MFMA | D: finalize f32,
// LDS h-write, ship h, out-stores, xp prefetch | barrier.
__global__ __launch_bounds__(256, 1) void rnn_k(
    const unsigned short* __restrict__ M, const float* __restrict__ xp,
    float* __restrict__ out, char* __restrict__ ws) {
  const int bid = blockIdx.x;
  if (bid & 4) return;
  const int g = bid & 3;
  const int role = bid >> 3;
  const int prole = 1 - role;
  const int tid = threadIdx.x;
  const int w = tid >> 6;      // 0..3
  const int lane = tid & 63;
  const int n = lane & 15;
  const int q = lane >> 4;     // 0..3
  const int colbase = role * 256 + w * 64;
  const int pcolbase = prole * 256 + w * 64;

  __shared__ __align__(16) unsigned short hb[2][16 * 512];
  __shared__ int sFast;

  {  // zero hb[0] (t=0 state): 16KB / 256 thr = 4 uint4
    uint4 z = {0, 0, 0, 0};
    uint4* p = (uint4*)&hb[0][0];
    #pragma unroll
    for (int i = 0; i < 4; i++) p[tid + 256 * i] = z;
  }

  unsigned* flags = (unsigned*)(ws + WS_FLAGS);
  unsigned* xcct = (unsigned*)(ws + WS_XCC);
  if (tid == 0) {
    unsigned myx;
    asm volatile("s_getreg_b32 %0, hwreg(HW_REG_XCC_ID)" : "=s"(myx));
    __hip_atomic_store(&xcct[bid], myx + 1, __ATOMIC_RELAXED, __HIP_MEMORY_SCOPE_AGENT);
    unsigned ox;
    while ((ox = __hip_atomic_load(&xcct[bid ^ 8], __ATOMIC_RELAXED,
                                   __HIP_MEMORY_SCOPE_AGENT)) == 0u)
      __builtin_amdgcn_s_sleep(2);
    sFast = (ox == myx + 1) ? 1 : 0;
  }

  const float C1 = (float)(1.0 - 16.67 / 100.0);

  // ---- weights: Bp[nt][kt] = M[col=colbase+nt*16+n][kt*32+q*8..+8] -> AGPRs
  V128 Bp[4][16];
  #pragma unroll
  for (int nt = 0; nt < 4; nt++) {
    const unsigned short* mb = M + (colbase + nt * 16 + n) * 512 + q * 8;
    #pragma unroll
    for (int kt = 0; kt < 16; kt++) Bp[nt][kt].u = *(const u32x4*)(mb + kt * 32);
  }
  #pragma unroll
  for (int nt = 0; nt < 4; nt++)
    #pragma unroll
    for (int kt = 0; kt < 16; kt++)
      asm volatile("" : "+a"(Bp[nt][kt].u));  // pin to AGPR class

  float hprev[4][4];
  #pragma unroll
  for (int a = 0; a < 4; a++)
    #pragma unroll
    for (int b = 0; b < 4; b++) hprev[a][b] = 0.f;

  const bool hasxp = (role == 0);
  const float* xpb = xp + ((g * 16 + 4 * q) << 8) + colbase + n;
  float xpA[4][4], xpB[4][4];
  #pragma unroll
  for (int a = 0; a < 4; a++)
    #pragma unroll
    for (int b = 0; b < 4; b++) { xpA[a][b] = 0.f; xpB[a][b] = 0.f; }
  if (hasxp) {
    #pragma unroll
    for (int nt = 0; nt < 4; nt++)
      #pragma unroll
      for (int j = 0; j < 4; j++) {
        xpA[nt][j] = __builtin_nontemporal_load(xpb + 0L * 16384 + j * 256 + nt * 16);
        xpB[nt][j] = __builtin_nontemporal_load(xpb + 1L * 16384 + j * 256 + nt * 16);
      }
  }

  float* outb = out + (long)(g * 16 + 4 * q) * (NT * NH) + colbase + n;

  // exchange addressing (payload blob is per-tid, 32B)
  char* Xb = ws + WS_X;
  char* xs0 = Xb + ((g * 2 + role) * 2 + 0) * 8192 + tid * 32;
  char* xs1 = Xb + ((g * 2 + role) * 2 + 1) * 8192 + tid * 32;
  const char* xr0 = Xb + ((g * 2 + prole) * 2 + 0) * 8192 + tid * 32;
  const char* xr1 = Xb + ((g * 2 + prole) * 2 + 1) * 8192 + tid * 32;
  unsigned* fs = flags + ((g * 2 + role) * 4 + w) * 16;
  unsigned* fr = flags + ((g * 2 + prole) * 4 + w) * 16;

  __syncthreads();
  const bool fastp = (sFast != 0);

  auto step = [&](unsigned short* hr, unsigned short* hw, int t,
                  float (&xpc)[4][4]) {
    // re-pin weights each step: blocks any hoisted VGPR mirrors (R4 failure)
    #pragma unroll
    for (int nt = 0; nt < 4; nt++)
      #pragma unroll
      for (int kt = 0; kt < 16; kt++)
        asm volatile("" : "+a"(Bp[nt][kt].u));

    // ---- recv: poll flag, issue payload loads (latency hidden by phase A)
    unsigned pd[8];
    if (t > 0) {
      const char* xb = (t & 1) ? xr1 : xr0;
      if (fastp) {
        while (*(volatile const unsigned*)fr < (unsigned)t)
          __builtin_amdgcn_s_sleep(1);
        volatile const unsigned* xv = (volatile const unsigned*)xb;
        #pragma unroll
        for (int i = 0; i < 8; i++) pd[i] = xv[i];
      } else {
        while (__hip_atomic_load(fr, __ATOMIC_RELAXED,
                                 __HIP_MEMORY_SCOPE_AGENT) < (unsigned)t)
          __builtin_amdgcn_s_sleep(1);
        #pragma unroll
        for (int i = 0; i < 4; i++) {
          ull u = __hip_atomic_load((const ull*)(xb + 8 * i), __ATOMIC_RELAXED,
                                    __HIP_MEMORY_SCOPE_AGENT);
          pd[2 * i] = (unsigned)u;
          pd[2 * i + 1] = (unsigned)(u >> 32);
        }
      }
    }

    f32x4 acc[4];
    #pragma unroll
    for (int nt = 0; nt < 4; nt++) acc[nt] = (f32x4){0.f, 0.f, 0.f, 0.f};

    // ---- phase A: MFMA over own k-half (h written locally last step)
    #pragma unroll
    for (int kt8 = 0; kt8 < 8; kt8++) {
      int kt = role * 8 + kt8;
      short8 a = *(const short8*)(hr + ((unsigned)(n * 512 + kt * 32 + q * 8) ^ SWZ(n)));
      #pragma unroll
      for (int nt = 0; nt < 4; nt++) acc[nt] = mfma16(a, Bp[nt][kt].s, acc[nt]);
    }

    // ---- scatter partner h into LDS (payload arrived during phase A)
    if (t > 0) {
      #pragma unroll
      for (int nt = 0; nt < 4; nt++) {
        #pragma unroll
        for (int jh = 0; jh < 2; jh++) {
          unsigned dv = pd[nt * 2 + jh];
          int r0 = 4 * q + 2 * jh, r1 = r0 + 1;
          int c = pcolbase + nt * 16 + n;
          hr[(unsigned)(r0 * 512 + c) ^ SWZ(r0)] = (unsigned short)dv;
          hr[(unsigned)(r1 * 512 + c) ^ SWZ(r1)] = (unsigned short)(dv >> 16);
        }
      }
    }
    asm volatile("s_waitcnt lgkmcnt(0)\n\ts_barrier" ::: "memory");  // barrier 1

    // ---- phase C: MFMA over partner k-half
    #pragma unroll
    for (int kt8 = 0; kt8 < 8; kt8++) {
      int kt = prole * 8 + kt8;
      short8 a = *(const short8*)(hr + ((unsigned)(n * 512 + kt * 32 + q * 8) ^ SWZ(n)));
      #pragma unroll
      for (int nt = 0; nt < 4; nt++) acc[nt] = mfma16(a, Bp[nt][kt].s, acc[nt]);
    }

    // ---- phase D: finalize f32; LDS h-write; ship; out; xp prefetch
    unsigned dw[8];
    #pragma unroll
    for (int nt = 0; nt < 4; nt++) {
      #pragma unroll
      for (int j = 0; j < 4; j++) {
        float v = fmaf(hprev[nt][j], C1, acc[nt][j] + xpc[nt][j]);
        v = fmaxf(v, 0.f);
        hprev[nt][j] = v;
      }
      asm("v_cvt_pk_bf16_f32 %0, %1, %2"
          : "=v"(dw[nt * 2]) : "v"(hprev[nt][0]), "v"(hprev[nt][1]));
      asm("v_cvt_pk_bf16_f32 %0, %1, %2"
          : "=v"(dw[nt * 2 + 1]) : "v"(hprev[nt][2]), "v"(hprev[nt][3]));
    }
    // own h -> LDS (next buffer), bf16 from packed dwords
    #pragma unroll
    for (int nt = 0; nt < 4; nt++) {
      #pragma unroll
      for (int jh = 0; jh < 2; jh++) {
        unsigned dv = dw[nt * 2 + jh];
        int r0 = 4 * q + 2 * jh, r1 = r0 + 1;
        int c = colbase + nt * 16 + n;
        hw[(unsigned)(r0 * 512 + c) ^ SWZ(r0)] = (unsigned short)dv;
        hw[(unsigned)(r1 * 512 + c) ^ SWZ(r1)] = (unsigned short)(dv >> 16);
      }
    }
    // ship h(t+1) to partner (32B blob)
    {
      char* xb = ((t + 1) & 1) ? xs1 : xs0;
      if (fastp) {
        uint4 v0 = {dw[0], dw[1], dw[2], dw[3]};
        uint4 v1 = {dw[4], dw[5], dw[6], dw[7]};
        *(uint4*)xb = v0;
        *(uint4*)(xb + 16) = v1;
        asm volatile("s_waitcnt vmcnt(0)" ::: "memory");
        if (lane == 0) *(volatile unsigned*)fs = (unsigned)(t + 1);
      } else {
        #pragma unroll
        for (int i = 0; i < 4; i++) {
          ull u = (ull)dw[2 * i] | ((ull)dw[2 * i + 1] << 32);
          __hip_atomic_store((ull*)(xb + 8 * i), u, __ATOMIC_RELAXED,
                             __HIP_MEMORY_SCOPE_AGENT);
        }
        if (lane == 0)
          __hip_atomic_store(fs, (unsigned)(t + 1), __ATOMIC_RELEASE,
                             __HIP_MEMORY_SCOPE_AGENT);
      }
    }
    // out-stores AFTER the flag: they ride across the barrier un-drained
    float* outt = outb + (long)t * NH;
    #pragma unroll
    for (int nt = 0; nt < 4; nt++)
      #pragma unroll
      for (int j = 0; j < 4; j++)
        __builtin_nontemporal_store(hprev[nt][j],
                                    outt + (long)j * (NT * NH) + nt * 16);
    if (hasxp) {
      int tn = t + 2; if (tn >= NT) tn = 0;  // wrap: values unused, stay valid
      const float* xpl = xpb + (long)tn * 16384;
      #pragma unroll
      for (int nt = 0; nt < 4; nt++)
        #pragma unroll
        for (int j = 0; j < 4; j++)
          xpc[nt][j] = __builtin_nontemporal_load(xpl + j * 256 + nt * 16);
    }
    asm volatile("s_waitcnt lgkmcnt(0)\n\ts_barrier" ::: "memory");  // barrier 2
  };

  #pragma unroll 1
  for (int t = 0; t < NT; t += 2) {
    step(hb[0], hb[1], t, xpA);
    step(hb[1], hb[0], t + 1, xpB);
  }

  // final h1, h2
  const long fbase = (long)NB * NT * NH;  // 33554432
  #pragma unroll
  for (int nt = 0; nt < 4; nt++) {
    #pragma unroll
    for (int j = 0; j < 4; j++) {
      int b = g * 16 + 4 * q + j;
      int col = colbase + nt * 16 + n;
      long off = (col < 256) ? (fbase + b * 256 + col)
                             : (fbase + 16384 + b * 256 + (col - 256));
      out[off] = hprev[nt][j];
    }
  }
}

extern "C" void kernel_launch(void* const* d_in, const int* in_sizes, int n_in,
                              void* d_out, int out_size, void* d_ws, size_t ws_size,
                              hipStream_t stream) {
  const float* x   = (const float*)d_in[0];
  const float* Wi  = (const float*)d_in[2];
  const float* bi  = (const float*)d_in[3];
  const float* W11 = (const float*)d_in[4];
  const float* W22 = (const float*)d_in[5];
  const float* W12 = (const float*)d_in[6];
  const float* W21 = (const float*)d_in[7];
  float* out = (float*)d_out;

  unsigned short* M = (unsigned short*)d_ws;
  float* WiT = (float*)((char*)d_ws + 524288);
  unsigned* ctrl = (unsigned*)((char*)d_ws + WS_FLAGS);
  float* xp = (float*)((char*)d_ws + WS_XP);

  buildM_k<<<1024, 256, 0, stream>>>(W11, W22, W12, W21, M, ctrl);
  buildWiT_k<<<128, 256, 0, stream>>>(Wi, WiT);
  xproj_k<<<1024, 256, 0, stream>>>(x, WiT, bi, xp);
  rnn_k<<<16, 256, 0, stream>>>(M, xp, out, (char*)d_ws);
}

// Round 7
// 3637.461 us; speedup vs baseline: 4.6743x; 4.6743x over previous
//
#include <hip/hip_runtime.h>

typedef short short8 __attribute__((ext_vector_type(8)));
typedef float f32x4 __attribute__((ext_vector_type(4)));
typedef unsigned int u32x4 __attribute__((ext_vector_type(4)));
typedef unsigned long long ull;

#define NB 64
#define NT 1024
#define NI 128
#define NH 512

// ws layout (bytes):
//   0        : M      512KB  combined recurrent matrix, bf16 [512][512]
//   524288   : WiT    128KB
//   655360   : X      128KB  h-half exchange: ((g*2+role)*2+parity)*8KB + tid*32
//   786432   : flags  4KB    ((g*2+role)*4+w)*64B, monotone seq
//   790528   : xcc    64B    per-bid xcc-id table
//   1048576  : xp     64MB   [t][b][256] f32
#define WS_X     655360
#define WS_FLAGS 786432
#define WS_XCC   790528
#define WS_XP    1048576

#define SWZ(m) ((unsigned)(((m) & 7) << 3))

__device__ __forceinline__ unsigned short f2bf(float f) {
  union { float f; unsigned u; } v; v.f = f;
  unsigned u = v.u;
  return (unsigned short)((u + 0x7FFFu + ((u >> 16) & 1u)) >> 16);
}

// Build combined recurrent matrix M[o][k] (512x512 bf16), scales folded in.
// Also zeroes flags/xcc (stream-ordered before rnn_k: graph-replay safe).
__global__ __launch_bounds__(256) void buildM_k(
    const float* __restrict__ W11, const float* __restrict__ W22,
    const float* __restrict__ W12, const float* __restrict__ W21,
    unsigned short* __restrict__ M, unsigned* __restrict__ ctrl) {
  if (blockIdx.x == 0) {
    #pragma unroll
    for (int i = 0; i < 8; i++) ctrl[threadIdx.x + 256 * i] = 0;  // 8KB
  }
  int idx = blockIdx.x * 256 + threadIdx.x;  // 262144 total
  int o = idx >> 9, k = idx & 511;
  const float A1f = (float)(16.67 / 100.0);
  float v;
  if (o < 256) {
    v = (k < 256) ? A1f * W11[(o << 8) + k]
                  : A1f * 0.5f * W21[(o << 8) + (k - 256)];
  } else {
    int o2 = o - 256;
    v = (k < 256) ? A1f * 0.5f * W12[(o2 << 8) + k]
                  : A1f * W22[(o2 << 8) + (k - 256)];
  }
  M[idx] = f2bf(v);
}

__global__ __launch_bounds__(256) void buildWiT_k(const float* __restrict__ Wi,
                                                  float* __restrict__ WiT) {
  int idx = blockIdx.x * 256 + threadIdx.x;  // 32768 = 128*256, WiT[k][o]
  int k = idx >> 8, o = idx & 255;
  WiT[idx] = Wi[o * 128 + k];
}

// xp'[t][b][o] = A1 * (sum_i x[b][t][i]*Wi[o][i] + bi[o]), f32, layout [t][b][o].
__global__ __launch_bounds__(256) void xproj_k(
    const float* __restrict__ x, const float* __restrict__ WiT,
    const float* __restrict__ bi, float* __restrict__ xp) {
  __shared__ float xs[128 * 68];
  int tid = threadIdx.x;
  int wv = tid >> 6;
  int c = tid & 63;
  long Rbase = (long)blockIdx.x * 64;
  const float* xg = x + Rbase * 128;
  #pragma unroll
  for (int i = 0; i < 32; i++) {
    int idx = tid + 256 * i;
    int r = idx >> 7, k = idx & 127;
    xs[k * 68 + r] = xg[idx];
  }
  __syncthreads();
  float acc[4][16];
  #pragma unroll
  for (int a = 0; a < 4; a++)
    #pragma unroll
    for (int b = 0; b < 16; b++) acc[a][b] = 0.f;
  for (int k = 0; k < 128; k++) {
    f32x4 w4 = *(const f32x4*)(WiT + k * 256 + 4 * c);
    const float* xr = &xs[k * 68 + 16 * wv];
    #pragma unroll
    for (int rr = 0; rr < 4; rr++) {
      f32x4 xv = *(const f32x4*)(xr + 4 * rr);
      #pragma unroll
      for (int cc = 0; cc < 4; cc++) {
        #pragma unroll
        for (int u = 0; u < 4; u++)
          acc[cc][4 * rr + u] = fmaf(w4[cc], xv[u], acc[cc][4 * rr + u]);
      }
    }
  }
  f32x4 bv = *(const f32x4*)(bi + 4 * c);
  const float A1f = (float)(16.67 / 100.0);
  #pragma unroll
  for (int rr = 0; rr < 16; rr++) {
    long R = Rbase + 16 * wv + rr;
    int b = (int)(R >> 10), t = (int)(R & 1023);
    f32x4 o;
    #pragma unroll
    for (int cc = 0; cc < 4; cc++) o[cc] = A1f * (acc[cc][rr] + bv[cc]);
    *(f32x4*)(xp + ((long)(t * 64 + b) << 8) + 4 * c) = o;
  }
}

// ---- hard-AGPR machinery -------------------------------------------------
// Weight quad (kt,nt) lives at physical AGPRs a[(kt*4+nt)*4 .. +3], written
// once via v_accvgpr_write. The compiler never owns these values: MFMA asm
// references literal a[N:N+3]. Clobbers make .agpr_count correct.
#define PINQ(W, R0, R1, R2, R3)                                   \
  asm volatile("v_accvgpr_write_b32 " R0 ", %0\n\t"               \
               "v_accvgpr_write_b32 " R1 ", %1\n\t"               \
               "v_accvgpr_write_b32 " R2 ", %2\n\t"               \
               "v_accvgpr_write_b32 " R3 ", %3"                   \
               :: "v"((W)[0]), "v"((W)[1]), "v"((W)[2]), "v"((W)[3]) \
               : R0, R1, R2, R3)

#define MF "v_mfma_f32_16x16x32_bf16 "
// One kt-group: 1 LDS A-load feeds 4 MFMAs (independent acc chains).
// PRE: "s_nop 1" on the first group of a phase covers the VALU(acc
// zero-init) -> MFMA SrcC read hazard (2 wait states). POST: "s_nop 7 +
// s_nop 1" inside the last blob covers MFMA write -> VALU read of acc.
#define KTG_B(AV, S0, S1, S2, S3, PRE, POST)                          \
  asm volatile(PRE MF "%0, %1, " S0 ", %0" : "+v"(acc[0]) : "v"(AV)); \
  asm volatile(MF "%0, %1, " S1 ", %0" : "+v"(acc[1]) : "v"(AV));     \
  asm volatile(MF "%0, %1, " S2 ", %0" : "+v"(acc[2]) : "v"(AV));     \
  asm volatile(MF "%0, %1, " S3 ", %0" POST : "+v"(acc[3]) : "v"(AV));
#define ALOADX(kt) \
  (*(const short8*)(hr + (((unsigned)(n * 512 + (kt) * 32 + q * 8)) ^ SWZ(n))))
#define KTG(kt, S0, S1, S2, S3)  { short8 av_ = ALOADX(kt); KTG_B(av_, S0, S1, S2, S3, "", "") }
#define KTGF(kt, S0, S1, S2, S3) { short8 av_ = ALOADX(kt); KTG_B(av_, S0, S1, S2, S3, "s_nop 1\n\t", "") }
#define KTGL(kt, S0, S1, S2, S3) { short8 av_ = ALOADX(kt); KTG_B(av_, S0, S1, S2, S3, "", "\n\ts_nop 7\n\ts_nop 1") }

// Recurrent kernel: output-split pairs, weights in PHYSICAL AGPRs a0-a255.
// grid 16; active bids {0..3}=role0 (cols 0..255), {8..11}=role1 (cols 256..511);
// pair (g, g+8). 256 threads = 4 waves (1/SIMD -> 512-reg unified budget:
// 256 AGPR weights + ~150 arch VGPR). Step: recv poll+loads (overlap phase A)
// | A: own-k MFMA (asm, hard AGPR) | scatter partner h -> LDS | barrier |
// C: partner-k MFMA | D: finalize f32, LDS h-write, ship h, out, xp | barrier.
__global__ __launch_bounds__(256, 1) void rnn_k(
    const unsigned short* __restrict__ M, const float* __restrict__ xp,
    float* __restrict__ out, char* __restrict__ ws) {
  const int bid = blockIdx.x;
  if (bid & 4) return;
  const int g = bid & 3;
  const int role = bid >> 3;
  const int prole = 1 - role;
  const int tid = threadIdx.x;
  const int w = tid >> 6;      // 0..3
  const int lane = tid & 63;
  const int n = lane & 15;
  const int q = lane >> 4;     // 0..3
  const int colbase = role * 256 + w * 64;
  const int pcolbase = prole * 256 + w * 64;

  __shared__ __align__(16) unsigned short hb[2][16 * 512];
  __shared__ int sFast;

  {  // zero hb[0] (t=0 state): 16KB / 256 thr = 4 uint4
    uint4 z = {0, 0, 0, 0};
    uint4* p = (uint4*)&hb[0][0];
    #pragma unroll
    for (int i = 0; i < 4; i++) p[tid + 256 * i] = z;
  }

  unsigned* flags = (unsigned*)(ws + WS_FLAGS);
  unsigned* xcct = (unsigned*)(ws + WS_XCC);
  if (tid == 0) {
    unsigned myx;
    asm volatile("s_getreg_b32 %0, hwreg(HW_REG_XCC_ID)" : "=s"(myx));
    __hip_atomic_store(&xcct[bid], myx + 1, __ATOMIC_RELAXED, __HIP_MEMORY_SCOPE_AGENT);
    unsigned ox;
    while ((ox = __hip_atomic_load(&xcct[bid ^ 8], __ATOMIC_RELAXED,
                                   __HIP_MEMORY_SCOPE_AGENT)) == 0u)
      __builtin_amdgcn_s_sleep(2);
    sFast = (ox == myx + 1) ? 1 : 0;
  }

  const float C1 = (float)(1.0 - 16.67 / 100.0);

  // ---- load weights into physical AGPRs (once) ----
  {
    const unsigned short* mb0 = M + (colbase + 0 * 16 + n) * 512 + q * 8;
    const unsigned short* mb1 = M + (colbase + 1 * 16 + n) * 512 + q * 8;
    const unsigned short* mb2 = M + (colbase + 2 * 16 + n) * 512 + q * 8;
    const unsigned short* mb3 = M + (colbase + 3 * 16 + n) * 512 + q * 8;
#define WQ0(kt) (*(const u32x4*)(mb0 + (kt) * 32))
#define WQ1(kt) (*(const u32x4*)(mb1 + (kt) * 32))
#define WQ2(kt) (*(const u32x4*)(mb2 + (kt) * 32))
#define WQ3(kt) (*(const u32x4*)(mb3 + (kt) * 32))
    PINQ(WQ0(0),  "a0",   "a1",   "a2",   "a3");
    PINQ(WQ1(0),  "a4",   "a5",   "a6",   "a7");
    PINQ(WQ2(0),  "a8",   "a9",   "a10",  "a11");
    PINQ(WQ3(0),  "a12",  "a13",  "a14",  "a15");
    PINQ(WQ0(1),  "a16",  "a17",  "a18",  "a19");
    PINQ(WQ1(1),  "a20",  "a21",  "a22",  "a23");
    PINQ(WQ2(1),  "a24",  "a25",  "a26",  "a27");
    PINQ(WQ3(1),  "a28",  "a29",  "a30",  "a31");
    PINQ(WQ0(2),  "a32",  "a33",  "a34",  "a35");
    PINQ(WQ1(2),  "a36",  "a37",  "a38",  "a39");
    PINQ(WQ2(2),  "a40",  "a41",  "a42",  "a43");
    PINQ(WQ3(2),  "a44",  "a45",  "a46",  "a47");
    PINQ(WQ0(3),  "a48",  "a49",  "a50",  "a51");
    PINQ(WQ1(3),  "a52",  "a53",  "a54",  "a55");
    PINQ(WQ2(3),  "a56",  "a57",  "a58",  "a59");
    PINQ(WQ3(3),  "a60",  "a61",  "a62",  "a63");
    PINQ(WQ0(4),  "a64",  "a65",  "a66",  "a67");
    PINQ(WQ1(4),  "a68",  "a69",  "a70",  "a71");
    PINQ(WQ2(4),  "a72",  "a73",  "a74",  "a75");
    PINQ(WQ3(4),  "a76",  "a77",  "a78",  "a79");
    PINQ(WQ0(5),  "a80",  "a81",  "a82",  "a83");
    PINQ(WQ1(5),  "a84",  "a85",  "a86",  "a87");
    PINQ(WQ2(5),  "a88",  "a89",  "a90",  "a91");
    PINQ(WQ3(5),  "a92",  "a93",  "a94",  "a95");
    PINQ(WQ0(6),  "a96",  "a97",  "a98",  "a99");
    PINQ(WQ1(6),  "a100", "a101", "a102", "a103");
    PINQ(WQ2(6),  "a104", "a105", "a106", "a107");
    PINQ(WQ3(6),  "a108", "a109", "a110", "a111");
    PINQ(WQ0(7),  "a112", "a113", "a114", "a115");
    PINQ(WQ1(7),  "a116", "a117", "a118", "a119");
    PINQ(WQ2(7),  "a120", "a121", "a122", "a123");
    PINQ(WQ3(7),  "a124", "a125", "a126", "a127");
    PINQ(WQ0(8),  "a128", "a129", "a130", "a131");
    PINQ(WQ1(8),  "a132", "a133", "a134", "a135");
    PINQ(WQ2(8),  "a136", "a137", "a138", "a139");
    PINQ(WQ3(8),  "a140", "a141", "a142", "a143");
    PINQ(WQ0(9),  "a144", "a145", "a146", "a147");
    PINQ(WQ1(9),  "a148", "a149", "a150", "a151");
    PINQ(WQ2(9),  "a152", "a153", "a154", "a155");
    PINQ(WQ3(9),  "a156", "a157", "a158", "a159");
    PINQ(WQ0(10), "a160", "a161", "a162", "a163");
    PINQ(WQ1(10), "a164", "a165", "a166", "a167");
    PINQ(WQ2(10), "a168", "a169", "a170", "a171");
    PINQ(WQ3(10), "a172", "a173", "a174", "a175");
    PINQ(WQ0(11), "a176", "a177", "a178", "a179");
    PINQ(WQ1(11), "a180", "a181", "a182", "a183");
    PINQ(WQ2(11), "a184", "a185", "a186", "a187");
    PINQ(WQ3(11), "a188", "a189", "a190", "a191");
    PINQ(WQ0(12), "a192", "a193", "a194", "a195");
    PINQ(WQ1(12), "a196", "a197", "a198", "a199");
    PINQ(WQ2(12), "a200", "a201", "a202", "a203");
    PINQ(WQ3(12), "a204", "a205", "a206", "a207");
    PINQ(WQ0(13), "a208", "a209", "a210", "a211");
    PINQ(WQ1(13), "a212", "a213", "a214", "a215");
    PINQ(WQ2(13), "a216", "a217", "a218", "a219");
    PINQ(WQ3(13), "a220", "a221", "a222", "a223");
    PINQ(WQ0(14), "a224", "a225", "a226", "a227");
    PINQ(WQ1(14), "a228", "a229", "a230", "a231");
    PINQ(WQ2(14), "a232", "a233", "a234", "a235");
    PINQ(WQ3(14), "a236", "a237", "a238", "a239");
    PINQ(WQ0(15), "a240", "a241", "a242", "a243");
    PINQ(WQ1(15), "a244", "a245", "a246", "a247");
    PINQ(WQ2(15), "a248", "a249", "a250", "a251");
    PINQ(WQ3(15), "a252", "a253", "a254", "a255");
  }

  float hprev[4][4];
  #pragma unroll
  for (int a = 0; a < 4; a++)
    #pragma unroll
    for (int b = 0; b < 4; b++) hprev[a][b] = 0.f;

  const bool hasxp = (role == 0);
  const float* xpb = xp + ((g * 16 + 4 * q) << 8) + colbase + n;
  float xpA[4][4], xpB[4][4];
  #pragma unroll
  for (int a = 0; a < 4; a++)
    #pragma unroll
    for (int b = 0; b < 4; b++) { xpA[a][b] = 0.f; xpB[a][b] = 0.f; }
  if (hasxp) {
    #pragma unroll
    for (int nt = 0; nt < 4; nt++)
      #pragma unroll
      for (int j = 0; j < 4; j++) {
        xpA[nt][j] = __builtin_nontemporal_load(xpb + 0L * 16384 + j * 256 + nt * 16);
        xpB[nt][j] = __builtin_nontemporal_load(xpb + 1L * 16384 + j * 256 + nt * 16);
      }
  }

  float* outb = out + (long)(g * 16 + 4 * q) * (NT * NH) + colbase + n;

  // exchange addressing (payload blob is per-tid, 32B)
  char* Xb = ws + WS_X;
  char* xs0 = Xb + ((g * 2 + role) * 2 + 0) * 8192 + tid * 32;
  char* xs1 = Xb + ((g * 2 + role) * 2 + 1) * 8192 + tid * 32;
  const char* xr0 = Xb + ((g * 2 + prole) * 2 + 0) * 8192 + tid * 32;
  const char* xr1 = Xb + ((g * 2 + prole) * 2 + 1) * 8192 + tid * 32;
  unsigned* fs = flags + ((g * 2 + role) * 4 + w) * 16;
  unsigned* fr = flags + ((g * 2 + prole) * 4 + w) * 16;

  __syncthreads();
  const bool fastp = (sFast != 0);

  auto step = [&](unsigned short* hr, unsigned short* hw, int t,
                  float (&xpc)[4][4]) {
    // ---- recv: poll flag, issue payload loads (latency hidden by phase A)
    unsigned pd[8];
    if (t > 0) {
      const char* xb = (t & 1) ? xr1 : xr0;
      if (fastp) {
        while (*(volatile const unsigned*)fr < (unsigned)t)
          __builtin_amdgcn_s_sleep(1);
        volatile const unsigned* xv = (volatile const unsigned*)xb;
        #pragma unroll
        for (int i = 0; i < 8; i++) pd[i] = xv[i];
      } else {
        while (__hip_atomic_load(fr, __ATOMIC_RELAXED,
                                 __HIP_MEMORY_SCOPE_AGENT) < (unsigned)t)
          __builtin_amdgcn_s_sleep(1);
        #pragma unroll
        for (int i = 0; i < 4; i++) {
          ull u = __hip_atomic_load((const ull*)(xb + 8 * i), __ATOMIC_RELAXED,
                                    __HIP_MEMORY_SCOPE_AGENT);
          pd[2 * i] = (unsigned)u;
          pd[2 * i + 1] = (unsigned)(u >> 32);
        }
      }
    }

    f32x4 acc[4];
    #pragma unroll
    for (int nt = 0; nt < 4; nt++) acc[nt] = (f32x4){0.f, 0.f, 0.f, 0.f};

    // ---- phase A: MFMA over own k-half (h written locally last step)
    if (role == 0) {
      KTGF(0, "a[0:3]",    "a[4:7]",    "a[8:11]",   "a[12:15]");
      KTG (1, "a[16:19]",  "a[20:23]",  "a[24:27]",  "a[28:31]");
      KTG (2, "a[32:35]",  "a[36:39]",  "a[40:43]",  "a[44:47]");
      KTG (3, "a[48:51]",  "a[52:55]",  "a[56:59]",  "a[60:63]");
      KTG (4, "a[64:67]",  "a[68:71]",  "a[72:75]",  "a[76:79]");
      KTG (5, "a[80:83]",  "a[84:87]",  "a[88:91]",  "a[92:95]");
      KTG (6, "a[96:99]",  "a[100:103]","a[104:107]","a[108:111]");
      KTG (7, "a[112:115]","a[116:119]","a[120:123]","a[124:127]");
    } else {
      KTGF(8,  "a[128:131]","a[132:135]","a[136:139]","a[140:143]");
      KTG (9,  "a[144:147]","a[148:151]","a[152:155]","a[156:159]");
      KTG (10, "a[160:163]","a[164:167]","a[168:171]","a[172:175]");
      KTG (11, "a[176:179]","a[180:183]","a[184:187]","a[188:191]");
      KTG (12, "a[192:195]","a[196:199]","a[200:203]","a[204:207]");
      KTG (13, "a[208:211]","a[212:215]","a[216:219]","a[220:223]");
      KTG (14, "a[224:227]","a[228:231]","a[232:235]","a[236:239]");
      KTG (15, "a[240:243]","a[244:247]","a[248:251]","a[252:255]");
    }

    // ---- scatter partner h into LDS (payload arrived during phase A)
    if (t > 0) {
      #pragma unroll
      for (int nt = 0; nt < 4; nt++) {
        #pragma unroll
        for (int jh = 0; jh < 2; jh++) {
          unsigned dv = pd[nt * 2 + jh];
          int r0 = 4 * q + 2 * jh, r1 = r0 + 1;
          int c = pcolbase + nt * 16 + n;
          hr[(unsigned)(r0 * 512 + c) ^ SWZ(r0)] = (unsigned short)dv;
          hr[(unsigned)(r1 * 512 + c) ^ SWZ(r1)] = (unsigned short)(dv >> 16);
        }
      }
    }
    asm volatile("s_waitcnt lgkmcnt(0)\n\ts_barrier" ::: "memory");  // barrier 1

    // ---- phase C: MFMA over partner k-half
    if (role == 0) {
      KTG (8,  "a[128:131]","a[132:135]","a[136:139]","a[140:143]");
      KTG (9,  "a[144:147]","a[148:151]","a[152:155]","a[156:159]");
      KTG (10, "a[160:163]","a[164:167]","a[168:171]","a[172:175]");
      KTG (11, "a[176:179]","a[180:183]","a[184:187]","a[188:191]");
      KTG (12, "a[192:195]","a[196:199]","a[200:203]","a[204:207]");
      KTG (13, "a[208:211]","a[212:215]","a[216:219]","a[220:223]");
      KTG (14, "a[224:227]","a[228:231]","a[232:235]","a[236:239]");
      KTGL(15, "a[240:243]","a[244:247]","a[248:251]","a[252:255]");
    } else {
      KTG (0, "a[0:3]",    "a[4:7]",    "a[8:11]",   "a[12:15]");
      KTG (1, "a[16:19]",  "a[20:23]",  "a[24:27]",  "a[28:31]");
      KTG (2, "a[32:35]",  "a[36:39]",  "a[40:43]",  "a[44:47]");
      KTG (3, "a[48:51]",  "a[52:55]",  "a[56:59]",  "a[60:63]");
      KTG (4, "a[64:67]",  "a[68:71]",  "a[72:75]",  "a[76:79]");
      KTG (5, "a[80:83]",  "a[84:87]",  "a[88:91]",  "a[92:95]");
      KTG (6, "a[96:99]",  "a[100:103]","a[104:107]","a[108:111]");
      KTGL(7, "a[112:115]","a[116:119]","a[120:123]","a[124:127]");
    }

    // ---- phase D: finalize f32; LDS h-write; ship; out; xp prefetch
    unsigned dw[8];
    #pragma unroll
    for (int nt = 0; nt < 4; nt++) {
      #pragma unroll
      for (int j = 0; j < 4; j++) {
        float v = fmaf(hprev[nt][j], C1, acc[nt][j] + xpc[nt][j]);
        v = fmaxf(v, 0.f);
        hprev[nt][j] = v;
      }
      asm("v_cvt_pk_bf16_f32 %0, %1, %2"
          : "=v"(dw[nt * 2]) : "v"(hprev[nt][0]), "v"(hprev[nt][1]));
      asm("v_cvt_pk_bf16_f32 %0, %1, %2"
          : "=v"(dw[nt * 2 + 1]) : "v"(hprev[nt][2]), "v"(hprev[nt][3]));
    }
    // own h -> LDS (next buffer), bf16 from packed dwords
    #pragma unroll
    for (int nt = 0; nt < 4; nt++) {
      #pragma unroll
      for (int jh = 0; jh < 2; jh++) {
        unsigned dv = dw[nt * 2 + jh];
        int r0 = 4 * q + 2 * jh, r1 = r0 + 1;
        int c = colbase + nt * 16 + n;
        hw[(unsigned)(r0 * 512 + c) ^ SWZ(r0)] = (unsigned short)dv;
        hw[(unsigned)(r1 * 512 + c) ^ SWZ(r1)] = (unsigned short)(dv >> 16);
      }
    }
    // ship h(t+1) to partner (32B blob)
    {
      char* xb = ((t + 1) & 1) ? xs1 : xs0;
      if (fastp) {
        uint4 v0 = {dw[0], dw[1], dw[2], dw[3]};
        uint4 v1 = {dw[4], dw[5], dw[6], dw[7]};
        *(uint4*)xb = v0;
        *(uint4*)(xb + 16) = v1;
        asm volatile("s_waitcnt vmcnt(0)" ::: "memory");
        if (lane == 0) *(volatile unsigned*)fs = (unsigned)(t + 1);
      } else {
        #pragma unroll
        for (int i = 0; i < 4; i++) {
          ull u = (ull)dw[2 * i] | ((ull)dw[2 * i + 1] << 32);
          __hip_atomic_store((ull*)(xb + 8 * i), u, __ATOMIC_RELAXED,
                             __HIP_MEMORY_SCOPE_AGENT);
        }
        if (lane == 0)
          __hip_atomic_store(fs, (unsigned)(t + 1), __ATOMIC_RELEASE,
                             __HIP_MEMORY_SCOPE_AGENT);
      }
    }
    // out-stores AFTER the flag: they ride across the barrier un-drained
    float* outt = outb + (long)t * NH;
    #pragma unroll
    for (int nt = 0; nt < 4; nt++)
      #pragma unroll
      for (int j = 0; j < 4; j++)
        __builtin_nontemporal_store(hprev[nt][j],
                                    outt + (long)j * (NT * NH) + nt * 16);
    if (hasxp) {
      int tn = t + 2; if (tn >= NT) tn = 0;  // wrap: values unused, stay valid
      const float* xpl = xpb + (long)tn * 16384;
      #pragma unroll
      for (int nt = 0; nt < 4; nt++)
        #pragma unroll
        for (int j = 0; j < 4; j++)
          xpc[nt][j] = __builtin_nontemporal_load(xpl + j * 256 + nt * 16);
    }
    asm volatile("s_waitcnt lgkmcnt(0)\n\ts_barrier" ::: "memory");  // barrier 2
  };

  #pragma unroll 1
  for (int t = 0; t < NT; t += 2) {
    step(hb[0], hb[1], t, xpA);
    step(hb[1], hb[0], t + 1, xpB);
  }

  // final h1, h2
  const long fbase = (long)NB * NT * NH;  // 33554432
  #pragma unroll
  for (int nt = 0; nt < 4; nt++) {
    #pragma unroll
    for (int j = 0; j < 4; j++) {
      int b = g * 16 + 4 * q + j;
      int col = colbase + nt * 16 + n;
      long off = (col < 256) ? (fbase + b * 256 + col)
                             : (fbase + 16384 + b * 256 + (col - 256));
      out[off] = hprev[nt][j];
    }
  }
}

extern "C" void kernel_launch(void* const* d_in, const int* in_sizes, int n_in,
                              void* d_out, int out_size, void* d_ws, size_t ws_size,
                              hipStream_t stream) {
  const float* x   = (const float*)d_in[0];
  const float* Wi  = (const float*)d_in[2];
  const float* bi  = (const float*)d_in[3];
  const float* W11 = (const float*)d_in[4];
  const float* W22 = (const float*)d_in[5];
  const float* W12 = (const float*)d_in[6];
  const float* W21 = (const float*)d_in[7];
  float* out = (float*)d_out;

  unsigned short* M = (unsigned short*)d_ws;
  float* WiT = (float*)((char*)d_ws + 524288);
  unsigned* ctrl = (unsigned*)((char*)d_ws + WS_FLAGS);
  float* xp = (float*)((char*)d_ws + WS_XP);

  buildM_k<<<1024, 256, 0, stream>>>(W11, W22, W12, W21, M, ctrl);
  buildWiT_k<<<128, 256, 0, stream>>>(Wi, WiT);
  xproj_k<<<1024, 256, 0, stream>>>(x, WiT, bi, xp);
  rnn_k<<<16, 256, 0, stream>>>(M, xp, out, (char*)d_ws);
}

// Round 8
// 3381.319 us; speedup vs baseline: 5.0283x; 1.0758x over previous
//
#include <hip/hip_runtime.h>

typedef short short8 __attribute__((ext_vector_type(8)));
typedef float f32x4 __attribute__((ext_vector_type(4)));
typedef unsigned int u32x4 __attribute__((ext_vector_type(4)));
typedef unsigned long long ull;

#define NB 64
#define NT 1024
#define NI 128
#define NH 512

// ws layout (bytes):
//   0        : M      512KB  combined recurrent matrix, bf16 [512][512]
//   524288   : WiT    128KB
//   655360   : X      128KB  h-half exchange: ((g*2+role)*2+parity)*8KB + tid*32
//   786432   : flags  4KB    ((g*2+role)*4+w)*64B, monotone seq
//   790528   : xcc    64B    per-bid xcc-id table
//   1048576  : xp     64MB   [t][b][256] f32
#define WS_X     655360
#define WS_FLAGS 786432
#define WS_XCC   790528
#define WS_XP    1048576

#define SWZ(m) ((unsigned)(((m) & 7) << 3))

__device__ __forceinline__ unsigned short f2bf(float f) {
  union { float f; unsigned u; } v; v.f = f;
  unsigned u = v.u;
  return (unsigned short)((u + 0x7FFFu + ((u >> 16) & 1u)) >> 16);
}

// Build combined recurrent matrix M[o][k] (512x512 bf16), scales folded in.
// Also zeroes flags/xcc (stream-ordered before rnn_k: graph-replay safe).
__global__ __launch_bounds__(256) void buildM_k(
    const float* __restrict__ W11, const float* __restrict__ W22,
    const float* __restrict__ W12, const float* __restrict__ W21,
    unsigned short* __restrict__ M, unsigned* __restrict__ ctrl) {
  if (blockIdx.x == 0) {
    #pragma unroll
    for (int i = 0; i < 8; i++) ctrl[threadIdx.x + 256 * i] = 0;  // 8KB
  }
  int idx = blockIdx.x * 256 + threadIdx.x;  // 262144 total
  int o = idx >> 9, k = idx & 511;
  const float A1f = (float)(16.67 / 100.0);
  float v;
  if (o < 256) {
    v = (k < 256) ? A1f * W11[(o << 8) + k]
                  : A1f * 0.5f * W21[(o << 8) + (k - 256)];
  } else {
    int o2 = o - 256;
    v = (k < 256) ? A1f * 0.5f * W12[(o2 << 8) + k]
                  : A1f * W22[(o2 << 8) + (k - 256)];
  }
  M[idx] = f2bf(v);
}

__global__ __launch_bounds__(256) void buildWiT_k(const float* __restrict__ Wi,
                                                  float* __restrict__ WiT) {
  int idx = blockIdx.x * 256 + threadIdx.x;  // 32768 = 128*256, WiT[k][o]
  int k = idx >> 8, o = idx & 255;
  WiT[idx] = Wi[o * 128 + k];
}

// xp'[t][b][o] = A1 * (sum_i x[b][t][i]*Wi[o][i] + bi[o]), f32, layout [t][b][o].
__global__ __launch_bounds__(256) void xproj_k(
    const float* __restrict__ x, const float* __restrict__ WiT,
    const float* __restrict__ bi, float* __restrict__ xp) {
  __shared__ float xs[128 * 68];
  int tid = threadIdx.x;
  int wv = tid >> 6;
  int c = tid & 63;
  long Rbase = (long)blockIdx.x * 64;
  const float* xg = x + Rbase * 128;
  #pragma unroll
  for (int i = 0; i < 32; i++) {
    int idx = tid + 256 * i;
    int r = idx >> 7, k = idx & 127;
    xs[k * 68 + r] = xg[idx];
  }
  __syncthreads();
  float acc[4][16];
  #pragma unroll
  for (int a = 0; a < 4; a++)
    #pragma unroll
    for (int b = 0; b < 16; b++) acc[a][b] = 0.f;
  for (int k = 0; k < 128; k++) {
    f32x4 w4 = *(const f32x4*)(WiT + k * 256 + 4 * c);
    const float* xr = &xs[k * 68 + 16 * wv];
    #pragma unroll
    for (int rr = 0; rr < 4; rr++) {
      f32x4 xv = *(const f32x4*)(xr + 4 * rr);
      #pragma unroll
      for (int cc = 0; cc < 4; cc++) {
        #pragma unroll
        for (int u = 0; u < 4; u++)
          acc[cc][4 * rr + u] = fmaf(w4[cc], xv[u], acc[cc][4 * rr + u]);
      }
    }
  }
  f32x4 bv = *(const f32x4*)(bi + 4 * c);
  const float A1f = (float)(16.67 / 100.0);
  #pragma unroll
  for (int rr = 0; rr < 16; rr++) {
    long R = Rbase + 16 * wv + rr;
    int b = (int)(R >> 10), t = (int)(R & 1023);
    f32x4 o;
    #pragma unroll
    for (int cc = 0; cc < 4; cc++) o[cc] = A1f * (acc[cc][rr] + bv[cc]);
    *(f32x4*)(xp + ((long)(t * 64 + b) << 8) + 4 * c) = o;
  }
}

// ---- hard-AGPR machinery -------------------------------------------------
// Weight quad (kt,nt) lives at physical AGPRs a[(kt*4+nt)*4 .. +3], written
// once via v_accvgpr_write. The compiler never owns these values: MFMA asm
// references literal a[N:N+3]. Clobbers make .agpr_count correct.
#define PINQ(W, R0, R1, R2, R3)                                   \
  asm volatile("v_accvgpr_write_b32 " R0 ", %0\n\t"               \
               "v_accvgpr_write_b32 " R1 ", %1\n\t"               \
               "v_accvgpr_write_b32 " R2 ", %2\n\t"               \
               "v_accvgpr_write_b32 " R3 ", %3"                   \
               :: "v"((W)[0]), "v"((W)[1]), "v"((W)[2]), "v"((W)[3]) \
               : R0, R1, R2, R3)

#define MF "v_mfma_f32_16x16x32_bf16 "
// One kt-group: A-fragment ALREADY in VGPRs (batched ds_reads issued before
// the blob -> LDS latency paid once, pipelined). 4 independent acc chains.
// PRE "s_nop 1": VALU(acc zero-init) -> MFMA SrcC hazard (2 wait states).
// POST "s_nop 7 + s_nop 1": MFMA write -> VALU read of acc in epilogue.
#define KTG_B(AV, S0, S1, S2, S3, PRE, POST)                          \
  asm volatile(PRE MF "%0, %1, " S0 ", %0" : "+v"(acc[0]) : "v"(AV)); \
  asm volatile(MF "%0, %1, " S1 ", %0" : "+v"(acc[1]) : "v"(AV));     \
  asm volatile(MF "%0, %1, " S2 ", %0" : "+v"(acc[2]) : "v"(AV));     \
  asm volatile(MF "%0, %1, " S3 ", %0" POST : "+v"(acc[3]) : "v"(AV));
#define KTG(i, S0, S1, S2, S3)  KTG_B(av[i], S0, S1, S2, S3, "", "")
#define KTGF(i, S0, S1, S2, S3) KTG_B(av[i], S0, S1, S2, S3, "s_nop 1\n\t", "")
#define KTGL(i, S0, S1, S2, S3) KTG_B(av[i], S0, S1, S2, S3, "", "\n\ts_nop 7\n\ts_nop 1")

// Recurrent kernel: output-split pairs, weights in PHYSICAL AGPRs a0-a255.
// grid 16; active bids {0..3}=role0 (cols 0..255), {8..11}=role1 (cols 256..511);
// pair (g, g+8) same-XCD under bid%8 round-robin (runtime-verified, L3 fallback).
// 256 threads = 4 waves (1/SIMD -> 512-reg unified budget: 256 AGPR + ~240 VGPR).
// Step (latency-overlapped): issue 8 A-frag ds_reads | poll+issue recv loads |
// MFMA-A (hides recv L2 latency) | scatter partner h | barrier1 | 8 C-frag
// ds_reads | MFMA-C | finalize f32 | SHIP EARLY (+flag) | xp prefetch |
// LDS h-write | out-stores | barrier2.
__global__ __launch_bounds__(256, 1) void rnn_k(
    const unsigned short* __restrict__ M, const float* __restrict__ xp,
    float* __restrict__ out, char* __restrict__ ws) {
  const int bid = blockIdx.x;
  if (bid & 4) return;
  const int g = bid & 3;
  const int role = bid >> 3;
  const int prole = 1 - role;
  const int tid = threadIdx.x;
  const int w = tid >> 6;      // 0..3
  const int lane = tid & 63;
  const int n = lane & 15;
  const int q = lane >> 4;     // 0..3
  const int colbase = role * 256 + w * 64;
  const int pcolbase = prole * 256 + w * 64;

  __shared__ __align__(16) unsigned short hb[2][16 * 512];
  __shared__ int sFast;

  {  // zero hb[0] (t=0 state): 16KB / 256 thr = 4 uint4
    uint4 z = {0, 0, 0, 0};
    uint4* p = (uint4*)&hb[0][0];
    #pragma unroll
    for (int i = 0; i < 4; i++) p[tid + 256 * i] = z;
  }

  unsigned* flags = (unsigned*)(ws + WS_FLAGS);
  unsigned* xcct = (unsigned*)(ws + WS_XCC);
  if (tid == 0) {
    unsigned myx;
    asm volatile("s_getreg_b32 %0, hwreg(HW_REG_XCC_ID)" : "=s"(myx));
    __hip_atomic_store(&xcct[bid], myx + 1, __ATOMIC_RELAXED, __HIP_MEMORY_SCOPE_AGENT);
    unsigned ox;
    while ((ox = __hip_atomic_load(&xcct[bid ^ 8], __ATOMIC_RELAXED,
                                   __HIP_MEMORY_SCOPE_AGENT)) == 0u)
      __builtin_amdgcn_s_sleep(2);
    sFast = (ox == myx + 1) ? 1 : 0;
  }

  const float C1 = (float)(1.0 - 16.67 / 100.0);

  // ---- load weights into physical AGPRs (once) ----
  {
    const unsigned short* mb0 = M + (colbase + 0 * 16 + n) * 512 + q * 8;
    const unsigned short* mb1 = M + (colbase + 1 * 16 + n) * 512 + q * 8;
    const unsigned short* mb2 = M + (colbase + 2 * 16 + n) * 512 + q * 8;
    const unsigned short* mb3 = M + (colbase + 3 * 16 + n) * 512 + q * 8;
#define WQ0(kt) (*(const u32x4*)(mb0 + (kt) * 32))
#define WQ1(kt) (*(const u32x4*)(mb1 + (kt) * 32))
#define WQ2(kt) (*(const u32x4*)(mb2 + (kt) * 32))
#define WQ3(kt) (*(const u32x4*)(mb3 + (kt) * 32))
    PINQ(WQ0(0),  "a0",   "a1",   "a2",   "a3");
    PINQ(WQ1(0),  "a4",   "a5",   "a6",   "a7");
    PINQ(WQ2(0),  "a8",   "a9",   "a10",  "a11");
    PINQ(WQ3(0),  "a12",  "a13",  "a14",  "a15");
    PINQ(WQ0(1),  "a16",  "a17",  "a18",  "a19");
    PINQ(WQ1(1),  "a20",  "a21",  "a22",  "a23");
    PINQ(WQ2(1),  "a24",  "a25",  "a26",  "a27");
    PINQ(WQ3(1),  "a28",  "a29",  "a30",  "a31");
    PINQ(WQ0(2),  "a32",  "a33",  "a34",  "a35");
    PINQ(WQ1(2),  "a36",  "a37",  "a38",  "a39");
    PINQ(WQ2(2),  "a40",  "a41",  "a42",  "a43");
    PINQ(WQ3(2),  "a44",  "a45",  "a46",  "a47");
    PINQ(WQ0(3),  "a48",  "a49",  "a50",  "a51");
    PINQ(WQ1(3),  "a52",  "a53",  "a54",  "a55");
    PINQ(WQ2(3),  "a56",  "a57",  "a58",  "a59");
    PINQ(WQ3(3),  "a60",  "a61",  "a62",  "a63");
    PINQ(WQ0(4),  "a64",  "a65",  "a66",  "a67");
    PINQ(WQ1(4),  "a68",  "a69",  "a70",  "a71");
    PINQ(WQ2(4),  "a72",  "a73",  "a74",  "a75");
    PINQ(WQ3(4),  "a76",  "a77",  "a78",  "a79");
    PINQ(WQ0(5),  "a80",  "a81",  "a82",  "a83");
    PINQ(WQ1(5),  "a84",  "a85",  "a86",  "a87");
    PINQ(WQ2(5),  "a88",  "a89",  "a90",  "a91");
    PINQ(WQ3(5),  "a92",  "a93",  "a94",  "a95");
    PINQ(WQ0(6),  "a96",  "a97",  "a98",  "a99");
    PINQ(WQ1(6),  "a100", "a101", "a102", "a103");
    PINQ(WQ2(6),  "a104", "a105", "a106", "a107");
    PINQ(WQ3(6),  "a108", "a109", "a110", "a111");
    PINQ(WQ0(7),  "a112", "a113", "a114", "a115");
    PINQ(WQ1(7),  "a116", "a117", "a118", "a119");
    PINQ(WQ2(7),  "a120", "a121", "a122", "a123");
    PINQ(WQ3(7),  "a124", "a125", "a126", "a127");
    PINQ(WQ0(8),  "a128", "a129", "a130", "a131");
    PINQ(WQ1(8),  "a132", "a133", "a134", "a135");
    PINQ(WQ2(8),  "a136", "a137", "a138", "a139");
    PINQ(WQ3(8),  "a140", "a141", "a142", "a143");
    PINQ(WQ0(9),  "a144", "a145", "a146", "a147");
    PINQ(WQ1(9),  "a148", "a149", "a150", "a151");
    PINQ(WQ2(9),  "a152", "a153", "a154", "a155");
    PINQ(WQ3(9),  "a156", "a157", "a158", "a159");
    PINQ(WQ0(10), "a160", "a161", "a162", "a163");
    PINQ(WQ1(10), "a164", "a165", "a166", "a167");
    PINQ(WQ2(10), "a168", "a169", "a170", "a171");
    PINQ(WQ3(10), "a172", "a173", "a174", "a175");
    PINQ(WQ0(11), "a176", "a177", "a178", "a179");
    PINQ(WQ1(11), "a180", "a181", "a182", "a183");
    PINQ(WQ2(11), "a184", "a185", "a186", "a187");
    PINQ(WQ3(11), "a188", "a189", "a190", "a191");
    PINQ(WQ0(12), "a192", "a193", "a194", "a195");
    PINQ(WQ1(12), "a196", "a197", "a198", "a199");
    PINQ(WQ2(12), "a200", "a201", "a202", "a203");
    PINQ(WQ3(12), "a204", "a205", "a206", "a207");
    PINQ(WQ0(13), "a208", "a209", "a210", "a211");
    PINQ(WQ1(13), "a212", "a213", "a214", "a215");
    PINQ(WQ2(13), "a216", "a217", "a218", "a219");
    PINQ(WQ3(13), "a220", "a221", "a222", "a223");
    PINQ(WQ0(14), "a224", "a225", "a226", "a227");
    PINQ(WQ1(14), "a228", "a229", "a230", "a231");
    PINQ(WQ2(14), "a232", "a233", "a234", "a235");
    PINQ(WQ3(14), "a236", "a237", "a238", "a239");
    PINQ(WQ0(15), "a240", "a241", "a242", "a243");
    PINQ(WQ1(15), "a244", "a245", "a246", "a247");
    PINQ(WQ2(15), "a248", "a249", "a250", "a251");
    PINQ(WQ3(15), "a252", "a253", "a254", "a255");
  }

  float hprev[4][4];
  #pragma unroll
  for (int a = 0; a < 4; a++)
    #pragma unroll
    for (int b = 0; b < 4; b++) hprev[a][b] = 0.f;

  const bool hasxp = (role == 0);
  const float* xpb = xp + ((g * 16 + 4 * q) << 8) + colbase + n;
  float xpA[4][4], xpB[4][4];
  #pragma unroll
  for (int a = 0; a < 4; a++)
    #pragma unroll
    for (int b = 0; b < 4; b++) { xpA[a][b] = 0.f; xpB[a][b] = 0.f; }
  if (hasxp) {
    #pragma unroll
    for (int nt = 0; nt < 4; nt++)
      #pragma unroll
      for (int j = 0; j < 4; j++) {
        xpA[nt][j] = __builtin_nontemporal_load(xpb + 0L * 16384 + j * 256 + nt * 16);
        xpB[nt][j] = __builtin_nontemporal_load(xpb + 1L * 16384 + j * 256 + nt * 16);
      }
  }

  float* outb = out + (long)(g * 16 + 4 * q) * (NT * NH) + colbase + n;

  // exchange addressing (payload blob is per-tid, 32B)
  char* Xb = ws + WS_X;
  char* xs0 = Xb + ((g * 2 + role) * 2 + 0) * 8192 + tid * 32;
  char* xs1 = Xb + ((g * 2 + role) * 2 + 1) * 8192 + tid * 32;
  const char* xr0 = Xb + ((g * 2 + prole) * 2 + 0) * 8192 + tid * 32;
  const char* xr1 = Xb + ((g * 2 + prole) * 2 + 1) * 8192 + tid * 32;
  unsigned* fs = flags + ((g * 2 + role) * 4 + w) * 16;
  unsigned* fr = flags + ((g * 2 + prole) * 4 + w) * 16;

  __syncthreads();
  const bool fastp = (sFast != 0);

  auto step = [&](unsigned short* hr, unsigned short* hw, int t,
                  float (&xpc)[4][4]) {
    const int role8 = role * 8, prole8 = prole * 8;
    short8 av[8];

    // ---- 1. batch-issue phase-A fragment reads (own k-half; pipelined)
    #pragma unroll
    for (int i = 0; i < 8; i++) {
      int kt = role8 + i;
      av[i] = *(const short8*)(hr + ((unsigned)(n * 512 + kt * 32 + q * 8) ^ SWZ(n)));
    }
    asm volatile("" ::: "memory");  // keep the ds_reads issued here

    // ---- 2. poll flag, issue recv loads (L2 latency hides under MFMA-A)
    unsigned pd[8];
    if (t > 0) {
      const char* xb = (t & 1) ? xr1 : xr0;
      if (fastp) {
        while (*(volatile const unsigned*)fr < (unsigned)t)
          __builtin_amdgcn_s_sleep(1);
        volatile const unsigned* xv = (volatile const unsigned*)xb;
        #pragma unroll
        for (int i = 0; i < 8; i++) pd[i] = xv[i];
      } else {
        while (__hip_atomic_load(fr, __ATOMIC_RELAXED,
                                 __HIP_MEMORY_SCOPE_AGENT) < (unsigned)t)
          __builtin_amdgcn_s_sleep(1);
        #pragma unroll
        for (int i = 0; i < 4; i++) {
          ull u = __hip_atomic_load((const ull*)(xb + 8 * i), __ATOMIC_RELAXED,
                                    __HIP_MEMORY_SCOPE_AGENT);
          pd[2 * i] = (unsigned)u;
          pd[2 * i + 1] = (unsigned)(u >> 32);
        }
      }
    }

    f32x4 acc[4];
    #pragma unroll
    for (int nt = 0; nt < 4; nt++) acc[nt] = (f32x4){0.f, 0.f, 0.f, 0.f};

    // ---- 3. phase A: MFMA over own k-half (A-frags already in VGPRs)
    if (role == 0) {
      KTGF(0, "a[0:3]",    "a[4:7]",    "a[8:11]",   "a[12:15]");
      KTG (1, "a[16:19]",  "a[20:23]",  "a[24:27]",  "a[28:31]");
      KTG (2, "a[32:35]",  "a[36:39]",  "a[40:43]",  "a[44:47]");
      KTG (3, "a[48:51]",  "a[52:55]",  "a[56:59]",  "a[60:63]");
      KTG (4, "a[64:67]",  "a[68:71]",  "a[72:75]",  "a[76:79]");
      KTG (5, "a[80:83]",  "a[84:87]",  "a[88:91]",  "a[92:95]");
      KTG (6, "a[96:99]",  "a[100:103]","a[104:107]","a[108:111]");
      KTG (7, "a[112:115]","a[116:119]","a[120:123]","a[124:127]");
    } else {
      KTGF(0, "a[128:131]","a[132:135]","a[136:139]","a[140:143]");
      KTG (1, "a[144:147]","a[148:151]","a[152:155]","a[156:159]");
      KTG (2, "a[160:163]","a[164:167]","a[168:171]","a[172:175]");
      KTG (3, "a[176:179]","a[180:183]","a[184:187]","a[188:191]");
      KTG (4, "a[192:195]","a[196:199]","a[200:203]","a[204:207]");
      KTG (5, "a[208:211]","a[212:215]","a[216:219]","a[220:223]");
      KTG (6, "a[224:227]","a[228:231]","a[232:235]","a[236:239]");
      KTG (7, "a[240:243]","a[244:247]","a[248:251]","a[252:255]");
    }

    // ---- 4. scatter partner h into LDS (payload arrived during phase A)
    if (t > 0) {
      #pragma unroll
      for (int nt = 0; nt < 4; nt++) {
        #pragma unroll
        for (int jh = 0; jh < 2; jh++) {
          unsigned dv = pd[nt * 2 + jh];
          int r0 = 4 * q + 2 * jh, r1 = r0 + 1;
          int c = pcolbase + nt * 16 + n;
          hr[(unsigned)(r0 * 512 + c) ^ SWZ(r0)] = (unsigned short)dv;
          hr[(unsigned)(r1 * 512 + c) ^ SWZ(r1)] = (unsigned short)(dv >> 16);
        }
      }
    }
    asm volatile("s_waitcnt lgkmcnt(0)\n\ts_barrier" ::: "memory");  // barrier 1

    // ---- 5. batch-issue phase-C fragment reads (partner k-half)
    #pragma unroll
    for (int i = 0; i < 8; i++) {
      int kt = prole8 + i;
      av[i] = *(const short8*)(hr + ((unsigned)(n * 512 + kt * 32 + q * 8) ^ SWZ(n)));
    }
    asm volatile("" ::: "memory");

    // ---- 6. phase C: MFMA over partner k-half
    if (role == 0) {
      KTG (0, "a[128:131]","a[132:135]","a[136:139]","a[140:143]");
      KTG (1, "a[144:147]","a[148:151]","a[152:155]","a[156:159]");
      KTG (2, "a[160:163]","a[164:167]","a[168:171]","a[172:175]");
      KTG (3, "a[176:179]","a[180:183]","a[184:187]","a[188:191]");
      KTG (4, "a[192:195]","a[196:199]","a[200:203]","a[204:207]");
      KTG (5, "a[208:211]","a[212:215]","a[216:219]","a[220:223]");
      KTG (6, "a[224:227]","a[228:231]","a[232:235]","a[236:239]");
      KTGL(7, "a[240:243]","a[244:247]","a[248:251]","a[252:255]");
    } else {
      KTG (0, "a[0:3]",    "a[4:7]",    "a[8:11]",   "a[12:15]");
      KTG (1, "a[16:19]",  "a[20:23]",  "a[24:27]",  "a[28:31]");
      KTG (2, "a[32:35]",  "a[36:39]",  "a[40:43]",  "a[44:47]");
      KTG (3, "a[48:51]",  "a[52:55]",  "a[56:59]",  "a[60:63]");
      KTG (4, "a[64:67]",  "a[68:71]",  "a[72:75]",  "a[76:79]");
      KTG (5, "a[80:83]",  "a[84:87]",  "a[88:91]",  "a[92:95]");
      KTG (6, "a[96:99]",  "a[100:103]","a[104:107]","a[108:111]");
      KTGL(7, "a[112:115]","a[116:119]","a[120:123]","a[124:127]");
    }

    // ---- 7. finalize f32; cvt; SHIP EARLY; then xp/LDS/out
    unsigned dw[8];
    #pragma unroll
    for (int nt = 0; nt < 4; nt++) {
      #pragma unroll
      for (int j = 0; j < 4; j++) {
        float v = fmaf(hprev[nt][j], C1, acc[nt][j] + xpc[nt][j]);
        v = fmaxf(v, 0.f);
        hprev[nt][j] = v;
      }
      asm("v_cvt_pk_bf16_f32 %0, %1, %2"
          : "=v"(dw[nt * 2]) : "v"(hprev[nt][0]), "v"(hprev[nt][1]));
      asm("v_cvt_pk_bf16_f32 %0, %1, %2"
          : "=v"(dw[nt * 2 + 1]) : "v"(hprev[nt][2]), "v"(hprev[nt][3]));
    }
    // ship h(t+1) to partner FIRST (partner's poll is waiting on this flag;
    // at this point all older vmem is >=1 step old, so vmcnt(0) ~= ship ack)
    {
      char* xb = ((t + 1) & 1) ? xs1 : xs0;
      if (fastp) {
        uint4 v0 = {dw[0], dw[1], dw[2], dw[3]};
        uint4 v1 = {dw[4], dw[5], dw[6], dw[7]};
        *(uint4*)xb = v0;
        *(uint4*)(xb + 16) = v1;
        asm volatile("s_waitcnt vmcnt(0)" ::: "memory");
        if (lane == 0) *(volatile unsigned*)fs = (unsigned)(t + 1);
      } else {
        #pragma unroll
        for (int i = 0; i < 4; i++) {
          ull u = (ull)dw[2 * i] | ((ull)dw[2 * i + 1] << 32);
          __hip_atomic_store((ull*)(xb + 8 * i), u, __ATOMIC_RELAXED,
                             __HIP_MEMORY_SCOPE_AGENT);
        }
        if (lane == 0)
          __hip_atomic_store(fs, (unsigned)(t + 1), __ATOMIC_RELEASE,
                             __HIP_MEMORY_SCOPE_AGENT);
      }
    }
    // xp prefetch for t+2 (issue early, consumed next-next step)
    if (hasxp) {
      int tn = t + 2; if (tn >= NT) tn = 0;  // wrap: values unused, stay valid
      const float* xpl = xpb + (long)tn * 16384;
      #pragma unroll
      for (int nt = 0; nt < 4; nt++)
        #pragma unroll
        for (int j = 0; j < 4; j++)
          xpc[nt][j] = __builtin_nontemporal_load(xpl + j * 256 + nt * 16);
    }
    // own h -> LDS (next buffer), bf16 from packed dwords
    #pragma unroll
    for (int nt = 0; nt < 4; nt++) {
      #pragma unroll
      for (int jh = 0; jh < 2; jh++) {
        unsigned dv = dw[nt * 2 + jh];
        int r0 = 4 * q + 2 * jh, r1 = r0 + 1;
        int c = colbase + nt * 16 + n;
        hw[(unsigned)(r0 * 512 + c) ^ SWZ(r0)] = (unsigned short)dv;
        hw[(unsigned)(r1 * 512 + c) ^ SWZ(r1)] = (unsigned short)(dv >> 16);
      }
    }
    // out-stores: fire-and-forget, ride across the barrier un-drained
    float* outt = outb + (long)t * NH;
    #pragma unroll
    for (int nt = 0; nt < 4; nt++)
      #pragma unroll
      for (int j = 0; j < 4; j++)
        __builtin_nontemporal_store(hprev[nt][j],
                                    outt + (long)j * (NT * NH) + nt * 16);
    asm volatile("s_waitcnt lgkmcnt(0)\n\ts_barrier" ::: "memory");  // barrier 2
  };

  #pragma unroll 1
  for (int t = 0; t < NT; t += 2) {
    step(hb[0], hb[1], t, xpA);
    step(hb[1], hb[0], t + 1, xpB);
  }

  // final h1, h2
  const long fbase = (long)NB * NT * NH;  // 33554432
  #pragma unroll
  for (int nt = 0; nt < 4; nt++) {
    #pragma unroll
    for (int j = 0; j < 4; j++) {
      int b = g * 16 + 4 * q + j;
      int col = colbase + nt * 16 + n;
      long off = (col < 256) ? (fbase + b * 256 + col)
                             : (fbase + 16384 + b * 256 + (col - 256));
      out[off] = hprev[nt][j];
    }
  }
}

extern "C" void kernel_launch(void* const* d_in, const int* in_sizes, int n_in,
                              void* d_out, int out_size, void* d_ws, size_t ws_size,
                              hipStream_t stream) {
  const float* x   = (const float*)d_in[0];
  const float* Wi  = (const float*)d_in[2];
  const float* bi  = (const float*)d_in[3];
  const float* W11 = (const float*)d_in[4];
  const float* W22 = (const float*)d_in[5];
  const float* W12 = (const float*)d_in[6];
  const float* W21 = (const float*)d_in[7];
  float* out = (float*)d_out;

  unsigned short* M = (unsigned short*)d_ws;
  float* WiT = (float*)((char*)d_ws + 524288);
  unsigned* ctrl = (unsigned*)((char*)d_ws + WS_FLAGS);
  float* xp = (float*)((char*)d_ws + WS_XP);

  buildM_k<<<1024, 256, 0, stream>>>(W11, W22, W12, W21, M, ctrl);
  buildWiT_k<<<128, 256, 0, stream>>>(Wi, WiT);
  xproj_k<<<1024, 256, 0, stream>>>(x, WiT, bi, xp);
  rnn_k<<<16, 256, 0, stream>>>(M, xp, out, (char*)d_ws);
}

// Round 11
// 2729.678 us; speedup vs baseline: 6.2287x; 1.2387x over previous
//
#include <hip/hip_runtime.h>

typedef short short8 __attribute__((ext_vector_type(8)));
typedef float f32x4 __attribute__((ext_vector_type(4)));
typedef unsigned int u32x4 __attribute__((ext_vector_type(4)));
typedef unsigned long long ull;

#define NB 64
#define NT 1024
#define NI 128
#define NH 512

// ws layout (bytes):
//   0        : M      512KB  combined recurrent matrix, bf16 [512][512]
//   524288   : WiT    128KB
//   655360   : X      128KB  h-half exchange: ((g*2+role)*2+parity)*8KB + tid*16
//   786432   : flags  4KB    ((g*2+role)*8+w)*64B, monotone seq
//   790528   : xcc    64B    per-bid xcc-id table
//   1048576  : xp     64MB   [t][b][256] f32
#define WS_X     655360
#define WS_FLAGS 786432
#define WS_XCC   790528
#define WS_XP    1048576

#define SWZ(m) ((unsigned)(((m) & 7) << 3))

__device__ __forceinline__ unsigned short f2bf(float f) {
  union { float f; unsigned u; } v; v.f = f;
  unsigned u = v.u;
  return (unsigned short)((u + 0x7FFFu + ((u >> 16) & 1u)) >> 16);
}

// Build combined recurrent matrix M[o][k] (512x512 bf16), scales folded in.
// Also zeroes flags/xcc (stream-ordered before rnn_k: graph-replay safe).
__global__ __launch_bounds__(256) void buildM_k(
    const float* __restrict__ W11, const float* __restrict__ W22,
    const float* __restrict__ W12, const float* __restrict__ W21,
    unsigned short* __restrict__ M, unsigned* __restrict__ ctrl) {
  if (blockIdx.x == 0) {
    #pragma unroll
    for (int i = 0; i < 8; i++) ctrl[threadIdx.x + 256 * i] = 0;  // 8KB
  }
  int idx = blockIdx.x * 256 + threadIdx.x;  // 262144 total
  int o = idx >> 9, k = idx & 511;
  const float A1f = (float)(16.67 / 100.0);
  float v;
  if (o < 256) {
    v = (k < 256) ? A1f * W11[(o << 8) + k]
                  : A1f * 0.5f * W21[(o << 8) + (k - 256)];
  } else {
    int o2 = o - 256;
    v = (k < 256) ? A1f * 0.5f * W12[(o2 << 8) + k]
                  : A1f * W22[(o2 << 8) + (k - 256)];
  }
  M[idx] = f2bf(v);
}

__global__ __launch_bounds__(256) void buildWiT_k(const float* __restrict__ Wi,
                                                  float* __restrict__ WiT) {
  int idx = blockIdx.x * 256 + threadIdx.x;  // 32768 = 128*256, WiT[k][o]
  int k = idx >> 8, o = idx & 255;
  WiT[idx] = Wi[o * 128 + k];
}

// xp'[t][b][o] = A1 * (sum_i x[b][t][i]*Wi[o][i] + bi[o]), f32, layout [t][b][o].
__global__ __launch_bounds__(256) void xproj_k(
    const float* __restrict__ x, const float* __restrict__ WiT,
    const float* __restrict__ bi, float* __restrict__ xp) {
  __shared__ float xs[128 * 68];
  int tid = threadIdx.x;
  int wv = tid >> 6;
  int c = tid & 63;
  long Rbase = (long)blockIdx.x * 64;
  const float* xg = x + Rbase * 128;
  #pragma unroll
  for (int i = 0; i < 32; i++) {
    int idx = tid + 256 * i;
    int r = idx >> 7, k = idx & 127;
    xs[k * 68 + r] = xg[idx];
  }
  __syncthreads();
  float acc[4][16];
  #pragma unroll
  for (int a = 0; a < 4; a++)
    #pragma unroll
    for (int b = 0; b < 16; b++) acc[a][b] = 0.f;
  for (int k = 0; k < 128; k++) {
    f32x4 w4 = *(const f32x4*)(WiT + k * 256 + 4 * c);
    const float* xr = &xs[k * 68 + 16 * wv];
    #pragma unroll
    for (int rr = 0; rr < 4; rr++) {
      f32x4 xv = *(const f32x4*)(xr + 4 * rr);
      #pragma unroll
      for (int cc = 0; cc < 4; cc++) {
        #pragma unroll
        for (int u = 0; u < 4; u++)
          acc[cc][4 * rr + u] = fmaf(w4[cc], xv[u], acc[cc][4 * rr + u]);
      }
    }
  }
  f32x4 bv = *(const f32x4*)(bi + 4 * c);
  const float A1f = (float)(16.67 / 100.0);
  #pragma unroll
  for (int rr = 0; rr < 16; rr++) {
    long R = Rbase + 16 * wv + rr;
    int b = (int)(R >> 10), t = (int)(R & 1023);
    f32x4 o;
    #pragma unroll
    for (int cc = 0; cc < 4; cc++) o[cc] = A1f * (acc[cc][rr] + bv[cc]);
    *(f32x4*)(xp + ((long)(t * 64 + b) << 8) + 4 * c) = o;
  }
}

// ---- hard-AGPR machinery -------------------------------------------------
// Weight quad (kt,nt) lives at physical AGPRs a[kt*8 + nt*4 .. +3] (kt 0..15,
// nt 0..1 -> a0..a127). Written once via v_accvgpr_write; MFMA asm references
// literal a[N:N+3]. PINQ clobbers make agpr_count=128 -> VGPR budget 128 at
// 2 waves/SIMD (launch_bounds(512,2), 256-reg unified budget per wave).
#define PINQ(W, R0, R1, R2, R3)                                   \
  asm volatile("v_accvgpr_write_b32 " R0 ", %0\n\t"               \
               "v_accvgpr_write_b32 " R1 ", %1\n\t"               \
               "v_accvgpr_write_b32 " R2 ", %2\n\t"               \
               "v_accvgpr_write_b32 " R3 ", %3"                   \
               :: "v"((W)[0]), "v"((W)[1]), "v"((W)[2]), "v"((W)[3]) \
               : R0, R1, R2, R3)

#define MF "v_mfma_f32_16x16x32_bf16 "
// One kt-group: A-fragment in VGPRs, 2 independent acc chains (nt=0,1).
// PRE "s_nop 1": VALU(acc init) -> MFMA SrcC hazard (2 wait states).
// POST "s_nop 7 + s_nop 1": MFMA write -> VALU read of acc in epilogue.
#define KTG_B(AV, S0, S1, PRE, POST)                                  \
  asm volatile(PRE MF "%0, %1, " S0 ", %0" : "+v"(acc[0]) : "v"(AV)); \
  asm volatile(MF "%0, %1, " S1 ", %0" POST : "+v"(acc[1]) : "v"(AV));
#define KTG(i, S0, S1)  KTG_B(av[i], S0, S1, "", "")
#define KTGF(i, S0, S1) KTG_B(av[i], S0, S1, "s_nop 1\n\t", "")
#define KTGL(i, S0, S1) KTG_B(av[i], S0, S1, "", "\n\ts_nop 7\n\ts_nop 1")

// Recurrent kernel: output-split pairs (R8 topology, PASSED), re-tiled to
// 8 waves x 128 AGPR for 2 waves/SIMD occupancy (R8's 6200 stall-cyc/step at
// 1 wave/SIMD had nothing to hide them; now the co-resident wave computes).
// grid 16; active bids {0..3}=role0 (cols 0..255), {8..11}=role1 (256..511);
// pair (g, g+8) same-XCD under bid%8 round-robin (runtime-verified, L3 fb).
// Wave w owns 32 cols over full K=512: 32 quads = 128 AGPRs + ~110 VGPR.
// Step: issue 8 A-frag ds_reads | poll+recv (16B/tid) | MFMA-A (own k-half)
// | scatter partner h -> LDS | barrier | 8 C-frag ds_reads | MFMA-C |
// finalize f32 | ship 16B + flag | xp prefetch | LDS h-write | out | barrier.
__global__ __launch_bounds__(512, 2) void rnn_k(
    const unsigned short* __restrict__ M, const float* __restrict__ xp,
    float* __restrict__ out, char* __restrict__ ws) {
  const int bid = blockIdx.x;
  if (bid & 4) return;
  const int g = bid & 3;
  const int role = bid >> 3;
  const int prole = 1 - role;
  const int tid = threadIdx.x;
  const int w = tid >> 6;      // 0..7
  const int lane = tid & 63;
  const int n = lane & 15;
  const int q = lane >> 4;     // 0..3
  const int colbase = role * 256 + w * 32;
  const int pcolbase = prole * 256 + w * 32;

  __shared__ __align__(16) unsigned short hb[2][16 * 512];
  __shared__ int sFast;

  {  // zero hb[0] (t=0 state): 16KB / 512 thr = 2 uint4
    uint4 z = {0, 0, 0, 0};
    uint4* p = (uint4*)&hb[0][0];
    p[tid] = z;
    p[tid + 512] = z;
  }

  unsigned* flags = (unsigned*)(ws + WS_FLAGS);
  unsigned* xcct = (unsigned*)(ws + WS_XCC);
  if (tid == 0) {
    unsigned myx;
    asm volatile("s_getreg_b32 %0, hwreg(HW_REG_XCC_ID)" : "=s"(myx));
    __hip_atomic_store(&xcct[bid], myx + 1, __ATOMIC_RELAXED, __HIP_MEMORY_SCOPE_AGENT);
    unsigned ox;
    while ((ox = __hip_atomic_load(&xcct[bid ^ 8], __ATOMIC_RELAXED,
                                   __HIP_MEMORY_SCOPE_AGENT)) == 0u)
      __builtin_amdgcn_s_sleep(2);
    sFast = (ox == myx + 1) ? 1 : 0;
  }

  const float C1 = (float)(1.0 - 16.67 / 100.0);

  // ---- load weights into physical AGPRs a0-a127 (once) ----
  {
    const unsigned short* mb0 = M + (colbase + 0 * 16 + n) * 512 + q * 8;
    const unsigned short* mb1 = M + (colbase + 1 * 16 + n) * 512 + q * 8;
#define WQ0(kt) (*(const u32x4*)(mb0 + (kt) * 32))
#define WQ1(kt) (*(const u32x4*)(mb1 + (kt) * 32))
    PINQ(WQ0(0),  "a0",   "a1",   "a2",   "a3");
    PINQ(WQ1(0),  "a4",   "a5",   "a6",   "a7");
    PINQ(WQ0(1),  "a8",   "a9",   "a10",  "a11");
    PINQ(WQ1(1),  "a12",  "a13",  "a14",  "a15");
    PINQ(WQ0(2),  "a16",  "a17",  "a18",  "a19");
    PINQ(WQ1(2),  "a20",  "a21",  "a22",  "a23");
    PINQ(WQ0(3),  "a24",  "a25",  "a26",  "a27");
    PINQ(WQ1(3),  "a28",  "a29",  "a30",  "a31");
    PINQ(WQ0(4),  "a32",  "a33",  "a34",  "a35");
    PINQ(WQ1(4),  "a36",  "a37",  "a38",  "a39");
    PINQ(WQ0(5),  "a40",  "a41",  "a42",  "a43");
    PINQ(WQ1(5),  "a44",  "a45",  "a46",  "a47");
    PINQ(WQ0(6),  "a48",  "a49",  "a50",  "a51");
    PINQ(WQ1(6),  "a52",  "a53",  "a54",  "a55");
    PINQ(WQ0(7),  "a56",  "a57",  "a58",  "a59");
    PINQ(WQ1(7),  "a60",  "a61",  "a62",  "a63");
    PINQ(WQ0(8),  "a64",  "a65",  "a66",  "a67");
    PINQ(WQ1(8),  "a68",  "a69",  "a70",  "a71");
    PINQ(WQ0(9),  "a72",  "a73",  "a74",  "a75");
    PINQ(WQ1(9),  "a76",  "a77",  "a78",  "a79");
    PINQ(WQ0(10), "a80",  "a81",  "a82",  "a83");
    PINQ(WQ1(10), "a84",  "a85",  "a86",  "a87");
    PINQ(WQ0(11), "a88",  "a89",  "a90",  "a91");
    PINQ(WQ1(11), "a92",  "a93",  "a94",  "a95");
    PINQ(WQ0(12), "a96",  "a97",  "a98",  "a99");
    PINQ(WQ1(12), "a100", "a101", "a102", "a103");
    PINQ(WQ0(13), "a104", "a105", "a106", "a107");
    PINQ(WQ1(13), "a108", "a109", "a110", "a111");
    PINQ(WQ0(14), "a112", "a113", "a114", "a115");
    PINQ(WQ1(14), "a116", "a117", "a118", "a119");
    PINQ(WQ0(15), "a120", "a121", "a122", "a123");
    PINQ(WQ1(15), "a124", "a125", "a126", "a127");
  }

  float hprev[2][4];
  #pragma unroll
  for (int a = 0; a < 2; a++)
    #pragma unroll
    for (int b = 0; b < 4; b++) hprev[a][b] = 0.f;

  const bool hasxp = (role == 0);
  const float* xpb = xp + ((g * 16 + 4 * q) << 8) + colbase + n;
  float xpA[2][4], xpB[2][4];
  #pragma unroll
  for (int a = 0; a < 2; a++)
    #pragma unroll
    for (int b = 0; b < 4; b++) { xpA[a][b] = 0.f; xpB[a][b] = 0.f; }
  if (hasxp) {
    #pragma unroll
    for (int nt = 0; nt < 2; nt++)
      #pragma unroll
      for (int j = 0; j < 4; j++) {
        xpA[nt][j] = __builtin_nontemporal_load(xpb + 0L * 16384 + j * 256 + nt * 16);
        xpB[nt][j] = __builtin_nontemporal_load(xpb + 1L * 16384 + j * 256 + nt * 16);
      }
  }

  float* outb = out + (long)(g * 16 + 4 * q) * (NT * NH) + colbase + n;

  // exchange addressing (payload blob is per-tid, 16B; 512 tid x 16B = 8KB/slot)
  char* Xb = ws + WS_X;
  char* xs0 = Xb + ((g * 2 + role) * 2 + 0) * 8192 + tid * 16;
  char* xs1 = Xb + ((g * 2 + role) * 2 + 1) * 8192 + tid * 16;
  const char* xr0 = Xb + ((g * 2 + prole) * 2 + 0) * 8192 + tid * 16;
  const char* xr1 = Xb + ((g * 2 + prole) * 2 + 1) * 8192 + tid * 16;
  unsigned* fs = flags + ((g * 2 + role) * 8 + w) * 16;
  unsigned* fr = flags + ((g * 2 + prole) * 8 + w) * 16;

  __syncthreads();
  const bool fastp = (sFast != 0);

  auto step = [&](unsigned short* hr, unsigned short* hw, int t,
                  float (&xpc)[2][4]) {
    const int role8 = role * 8, prole8 = prole * 8;
    short8 av[8];

    // ---- 1. batch-issue phase-A fragment reads (own k-half; pipelined)
    #pragma unroll
    for (int i = 0; i < 8; i++) {
      int kt = role8 + i;
      av[i] = *(const short8*)(hr + ((unsigned)(n * 512 + kt * 32 + q * 8) ^ SWZ(n)));
    }
    asm volatile("" ::: "memory");  // keep the ds_reads issued here

    // ---- 2. poll flag, issue recv loads (latency hides under MFMA-A)
    unsigned pd[4];
    if (t > 0) {
      const char* xb = (t & 1) ? xr1 : xr0;
      if (fastp) {
        while (*(volatile const unsigned*)fr < (unsigned)t)
          __builtin_amdgcn_s_sleep(1);
        volatile const unsigned* xv = (volatile const unsigned*)xb;
        #pragma unroll
        for (int i = 0; i < 4; i++) pd[i] = xv[i];
      } else {
        while (__hip_atomic_load(fr, __ATOMIC_RELAXED,
                                 __HIP_MEMORY_SCOPE_AGENT) < (unsigned)t)
          __builtin_amdgcn_s_sleep(1);
        #pragma unroll
        for (int i = 0; i < 2; i++) {
          ull u = __hip_atomic_load((const ull*)(xb + 8 * i), __ATOMIC_RELAXED,
                                    __HIP_MEMORY_SCOPE_AGENT);
          pd[2 * i] = (unsigned)u;
          pd[2 * i + 1] = (unsigned)(u >> 32);
        }
      }
    }

    f32x4 acc[2];
    acc[0] = (f32x4){0.f, 0.f, 0.f, 0.f};
    acc[1] = (f32x4){0.f, 0.f, 0.f, 0.f};

    // ---- 3. phase A: MFMA over own k-half (h written locally last step)
    if (role == 0) {
      KTGF(0, "a[0:3]",    "a[4:7]");
      KTG (1, "a[8:11]",   "a[12:15]");
      KTG (2, "a[16:19]",  "a[20:23]");
      KTG (3, "a[24:27]",  "a[28:31]");
      KTG (4, "a[32:35]",  "a[36:39]");
      KTG (5, "a[40:43]",  "a[44:47]");
      KTG (6, "a[48:51]",  "a[52:55]");
      KTG (7, "a[56:59]",  "a[60:63]");
    } else {
      KTGF(0, "a[64:67]",  "a[68:71]");
      KTG (1, "a[72:75]",  "a[76:79]");
      KTG (2, "a[80:83]",  "a[84:87]");
      KTG (3, "a[88:91]",  "a[92:95]");
      KTG (4, "a[96:99]",  "a[100:103]");
      KTG (5, "a[104:107]","a[108:111]");
      KTG (6, "a[112:115]","a[116:119]");
      KTG (7, "a[120:123]","a[124:127]");
    }

    // ---- 4. scatter partner h into LDS (payload arrived during phase A)
    if (t > 0) {
      #pragma unroll
      for (int nt = 0; nt < 2; nt++) {
        #pragma unroll
        for (int jh = 0; jh < 2; jh++) {
          unsigned dv = pd[nt * 2 + jh];
          int r0 = 4 * q + 2 * jh, r1 = r0 + 1;
          int c = pcolbase + nt * 16 + n;
          hr[(unsigned)(r0 * 512 + c) ^ SWZ(r0)] = (unsigned short)dv;
          hr[(unsigned)(r1 * 512 + c) ^ SWZ(r1)] = (unsigned short)(dv >> 16);
        }
      }
    }
    asm volatile("s_waitcnt lgkmcnt(0)\n\ts_barrier" ::: "memory");  // barrier 1

    // ---- 5. batch-issue phase-C fragment reads (partner k-half)
    #pragma unroll
    for (int i = 0; i < 8; i++) {
      int kt = prole8 + i;
      av[i] = *(const short8*)(hr + ((unsigned)(n * 512 + kt * 32 + q * 8) ^ SWZ(n)));
    }
    asm volatile("" ::: "memory");

    // ---- 6. phase C: MFMA over partner k-half
    if (role == 0) {
      KTG (0, "a[64:67]",  "a[68:71]");
      KTG (1, "a[72:75]",  "a[76:79]");
      KTG (2, "a[80:83]",  "a[84:87]");
      KTG (3, "a[88:91]",  "a[92:95]");
      KTG (4, "a[96:99]",  "a[100:103]");
      KTG (5, "a[104:107]","a[108:111]");
      KTG (6, "a[112:115]","a[116:119]");
      KTGL(7, "a[120:123]","a[124:127]");
    } else {
      KTG (0, "a[0:3]",    "a[4:7]");
      KTG (1, "a[8:11]",   "a[12:15]");
      KTG (2, "a[16:19]",  "a[20:23]");
      KTG (3, "a[24:27]",  "a[28:31]");
      KTG (4, "a[32:35]",  "a[36:39]");
      KTG (5, "a[40:43]",  "a[44:47]");
      KTG (6, "a[48:51]",  "a[52:55]");
      KTGL(7, "a[56:59]",  "a[60:63]");
    }

    // ---- 7. finalize f32; cvt; ship 16B + flag; then xp/LDS/out
    unsigned dw[4];
    #pragma unroll
    for (int nt = 0; nt < 2; nt++) {
      #pragma unroll
      for (int j = 0; j < 4; j++) {
        float v = fmaf(hprev[nt][j], C1, acc[nt][j] + xpc[nt][j]);
        v = fmaxf(v, 0.f);
        hprev[nt][j] = v;
      }
      asm("v_cvt_pk_bf16_f32 %0, %1, %2"
          : "=v"(dw[nt * 2]) : "v"(hprev[nt][0]), "v"(hprev[nt][1]));
      asm("v_cvt_pk_bf16_f32 %0, %1, %2"
          : "=v"(dw[nt * 2 + 1]) : "v"(hprev[nt][2]), "v"(hprev[nt][3]));
    }
    // ship h(t+1) to partner FIRST (partner's poll waits on this flag;
    // older vmem is >=1 step old, so vmcnt(0) ~= this store's ack)
    {
      char* xb = ((t + 1) & 1) ? xs1 : xs0;
      if (fastp) {
        uint4 v0 = {dw[0], dw[1], dw[2], dw[3]};
        *(uint4*)xb = v0;
        asm volatile("s_waitcnt vmcnt(0)" ::: "memory");
        if (lane == 0) *(volatile unsigned*)fs = (unsigned)(t + 1);
      } else {
        #pragma unroll
        for (int i = 0; i < 2; i++) {
          ull u = (ull)dw[2 * i] | ((ull)dw[2 * i + 1] << 32);
          __hip_atomic_store((ull*)(xb + 8 * i), u, __ATOMIC_RELAXED,
                             __HIP_MEMORY_SCOPE_AGENT);
        }
        if (lane == 0)
          __hip_atomic_store(fs, (unsigned)(t + 1), __ATOMIC_RELEASE,
                             __HIP_MEMORY_SCOPE_AGENT);
      }
    }
    // xp prefetch for t+2
    if (hasxp) {
      int tn = t + 2; if (tn >= NT) tn = 0;  // wrap: values unused, stay valid
      const float* xpl = xpb + (long)tn * 16384;
      #pragma unroll
      for (int nt = 0; nt < 2; nt++)
        #pragma unroll
        for (int j = 0; j < 4; j++)
          xpc[nt][j] = __builtin_nontemporal_load(xpl + j * 256 + nt * 16);
    }
    // own h -> LDS (next buffer), bf16 from packed dwords
    #pragma unroll
    for (int nt = 0; nt < 2; nt++) {
      #pragma unroll
      for (int jh = 0; jh < 2; jh++) {
        unsigned dv = dw[nt * 2 + jh];
        int r0 = 4 * q + 2 * jh, r1 = r0 + 1;
        int c = colbase + nt * 16 + n;
        hw[(unsigned)(r0 * 512 + c) ^ SWZ(r0)] = (unsigned short)dv;
        hw[(unsigned)(r1 * 512 + c) ^ SWZ(r1)] = (unsigned short)(dv >> 16);
      }
    }
    // out-stores: fire-and-forget, ride across the barrier un-drained
    float* outt = outb + (long)t * NH;
    #pragma unroll
    for (int nt = 0; nt < 2; nt++)
      #pragma unroll
      for (int j = 0; j < 4; j++)
        __builtin_nontemporal_store(hprev[nt][j],
                                    outt + (long)j * (NT * NH) + nt * 16);
    asm volatile("s_waitcnt lgkmcnt(0)\n\ts_barrier" ::: "memory");  // barrier 2
  };

  #pragma unroll 1
  for (int t = 0; t < NT; t += 2) {
    step(hb[0], hb[1], t, xpA);
    step(hb[1], hb[0], t + 1, xpB);
  }

  // final h1, h2
  const long fbase = (long)NB * NT * NH;  // 33554432
  #pragma unroll
  for (int nt = 0; nt < 2; nt++) {
    #pragma unroll
    for (int j = 0; j < 4; j++) {
      int b = g * 16 + 4 * q + j;
      int col = colbase + nt * 16 + n;
      long off = (col < 256) ? (fbase + b * 256 + col)
                             : (fbase + 16384 + b * 256 + (col - 256));
      out[off] = hprev[nt][j];
    }
  }
}

extern "C" void kernel_launch(void* const* d_in, const int* in_sizes, int n_in,
                              void* d_out, int out_size, void* d_ws, size_t ws_size,
                              hipStream_t stream) {
  const float* x   = (const float*)d_in[0];
  const float* Wi  = (const float*)d_in[2];
  const float* bi  = (const float*)d_in[3];
  const float* W11 = (const float*)d_in[4];
  const float* W22 = (const float*)d_in[5];
  const float* W12 = (const float*)d_in[6];
  const float* W21 = (const float*)d_in[7];
  float* out = (float*)d_out;

  unsigned short* M = (unsigned short*)d_ws;
  float* WiT = (float*)((char*)d_ws + 524288);
  unsigned* ctrl = (unsigned*)((char*)d_ws + WS_FLAGS);
  float* xp = (float*)((char*)d_ws + WS_XP);

  buildM_k<<<1024, 256, 0, stream>>>(W11, W22, W12, W21, M, ctrl);
  buildWiT_k<<<128, 256, 0, stream>>>(Wi, WiT);
  xproj_k<<<1024, 256, 0, stream>>>(x, WiT, bi, xp);
  rnn_k<<<16, 512, 0, stream>>>(M, xp, out, (char*)d_ws);
}

// Round 12
// 2594.813 us; speedup vs baseline: 6.5525x; 1.0520x over previous
//
#include <hip/hip_runtime.h>

typedef short short8 __attribute__((ext_vector_type(8)));
typedef float f32x4 __attribute__((ext_vector_type(4)));
typedef unsigned int u32x4 __attribute__((ext_vector_type(4)));
typedef unsigned long long ull;

#define NB 64
#define NT 1024
#define NI 128
#define NH 512

// ws layout (bytes):
//   0        : M      512KB  combined recurrent matrix, bf16 [512][512]
//   524288   : WiT    128KB
//   655360   : X      128KB  h-half exchange: ((g*2+role)*2+parity)*8KB + tid*16
//   786432   : flags  4KB    ((g*2+role)*8+w)*64B, monotone seq
//   790528   : xcc    64B    per-bid xcc-id table
//   1048576  : xp     64MB   [t][b][256] f32
#define WS_X     655360
#define WS_FLAGS 786432
#define WS_XCC   790528
#define WS_XP    1048576

#define SWZ(m) ((unsigned)(((m) & 7) << 3))

__device__ __forceinline__ unsigned short f2bf(float f) {
  union { float f; unsigned u; } v; v.f = f;
  unsigned u = v.u;
  return (unsigned short)((u + 0x7FFFu + ((u >> 16) & 1u)) >> 16);
}

// Build combined recurrent matrix M[o][k] (512x512 bf16), scales folded in.
// Also zeroes flags/xcc (stream-ordered before rnn_k: graph-replay safe).
__global__ __launch_bounds__(256) void buildM_k(
    const float* __restrict__ W11, const float* __restrict__ W22,
    const float* __restrict__ W12, const float* __restrict__ W21,
    unsigned short* __restrict__ M, unsigned* __restrict__ ctrl) {
  if (blockIdx.x == 0) {
    #pragma unroll
    for (int i = 0; i < 8; i++) ctrl[threadIdx.x + 256 * i] = 0;  // 8KB
  }
  int idx = blockIdx.x * 256 + threadIdx.x;  // 262144 total
  int o = idx >> 9, k = idx & 511;
  const float A1f = (float)(16.67 / 100.0);
  float v;
  if (o < 256) {
    v = (k < 256) ? A1f * W11[(o << 8) + k]
                  : A1f * 0.5f * W21[(o << 8) + (k - 256)];
  } else {
    int o2 = o - 256;
    v = (k < 256) ? A1f * 0.5f * W12[(o2 << 8) + k]
                  : A1f * W22[(o2 << 8) + (k - 256)];
  }
  M[idx] = f2bf(v);
}

__global__ __launch_bounds__(256) void buildWiT_k(const float* __restrict__ Wi,
                                                  float* __restrict__ WiT) {
  int idx = blockIdx.x * 256 + threadIdx.x;  // 32768 = 128*256, WiT[k][o]
  int k = idx >> 8, o = idx & 255;
  WiT[idx] = Wi[o * 128 + k];
}

// xp'[t][b][o] = A1 * (sum_i x[b][t][i]*Wi[o][i] + bi[o]), f32, layout [t][b][o].
__global__ __launch_bounds__(256) void xproj_k(
    const float* __restrict__ x, const float* __restrict__ WiT,
    const float* __restrict__ bi, float* __restrict__ xp) {
  __shared__ float xs[128 * 68];
  int tid = threadIdx.x;
  int wv = tid >> 6;
  int c = tid & 63;
  long Rbase = (long)blockIdx.x * 64;
  const float* xg = x + Rbase * 128;
  #pragma unroll
  for (int i = 0; i < 32; i++) {
    int idx = tid + 256 * i;
    int r = idx >> 7, k = idx & 127;
    xs[k * 68 + r] = xg[idx];
  }
  __syncthreads();
  float acc[4][16];
  #pragma unroll
  for (int a = 0; a < 4; a++)
    #pragma unroll
    for (int b = 0; b < 16; b++) acc[a][b] = 0.f;
  for (int k = 0; k < 128; k++) {
    f32x4 w4 = *(const f32x4*)(WiT + k * 256 + 4 * c);
    const float* xr = &xs[k * 68 + 16 * wv];
    #pragma unroll
    for (int rr = 0; rr < 4; rr++) {
      f32x4 xv = *(const f32x4*)(xr + 4 * rr);
      #pragma unroll
      for (int cc = 0; cc < 4; cc++) {
        #pragma unroll
        for (int u = 0; u < 4; u++)
          acc[cc][4 * rr + u] = fmaf(w4[cc], xv[u], acc[cc][4 * rr + u]);
      }
    }
  }
  f32x4 bv = *(const f32x4*)(bi + 4 * c);
  const float A1f = (float)(16.67 / 100.0);
  #pragma unroll
  for (int rr = 0; rr < 16; rr++) {
    long R = Rbase + 16 * wv + rr;
    int b = (int)(R >> 10), t = (int)(R & 1023);
    f32x4 o;
    #pragma unroll
    for (int cc = 0; cc < 4; cc++) o[cc] = A1f * (acc[cc][rr] + bv[cc]);
    *(f32x4*)(xp + ((long)(t * 64 + b) << 8) + 4 * c) = o;
  }
}

// ---- hard-AGPR machinery -------------------------------------------------
// Weight quad (kt,nt) lives at physical AGPRs a[kt*8 + nt*4 .. +3] (kt 0..15
// over FULL K, nt 0..1 -> a0..a127). Written once via v_accvgpr_write; MFMA
// asm references literal a[N:N+3]. agpr_count=128 -> 2 waves/SIMD at
// launch_bounds(512,2) (256-reg unified budget per wave).
#define PINQ(W, R0, R1, R2, R3)                                   \
  asm volatile("v_accvgpr_write_b32 " R0 ", %0\n\t"               \
               "v_accvgpr_write_b32 " R1 ", %1\n\t"               \
               "v_accvgpr_write_b32 " R2 ", %2\n\t"               \
               "v_accvgpr_write_b32 " R3 ", %3"                   \
               :: "v"((W)[0]), "v"((W)[1]), "v"((W)[2]), "v"((W)[3]) \
               : R0, R1, R2, R3)

#define MF "v_mfma_f32_16x16x32_bf16 "
// One kt-group: A-fragment in VGPRs, 2 independent acc chains (nt=0,1).
// PRE "s_nop 1": VALU(acc init) -> MFMA SrcC hazard (2 wait states).
// POST "s_nop 7 + s_nop 1": MFMA write -> VALU read of acc in epilogue.
#define KTG_B(AV, S0, S1, PRE, POST)                                  \
  asm volatile(PRE MF "%0, %1, " S0 ", %0" : "+v"(acc[0]) : "v"(AV)); \
  asm volatile(MF "%0, %1, " S1 ", %0" POST : "+v"(acc[1]) : "v"(AV));
#define KTG(i, S0, S1)  KTG_B(av[i], S0, S1, "", "")
#define KTGF(i, S0, S1) KTG_B(av[i], S0, S1, "s_nop 1\n\t", "")
#define KTGL(i, S0, S1) KTG_B(av[i], S0, S1, "", "\n\ts_nop 7\n\ts_nop 1")

// Recurrent kernel: output-split pairs, 8 waves x 128 AGPR (R11 base, PASSED),
// restructured to a SINGLE barrier per step. Key invariant: hr is read-only
// for the whole step (partner h for step t was scattered into hr at the END
// of step t-1), so the A/C phase split and its barrier are unnecessary --
// one fused 16-kt MFMA run. Poll+recv+scatter move to the epilogue next to
// the own-h write (both target hw), overlapped with out/xp stores.
// grid 16; active bids {0..3}=role0 (cols 0..255), {8..11}=role1 (256..511);
// pair (g, g+8) same-XCD under bid%8 round-robin (runtime-verified, L3 fb).
// Step: 8 ds_reads kt0-7 | MFMA kt0-7 | 8 ds_reads kt8-15 | MFMA kt8-15 |
// finalize f32 | ship h(t+1)+flag | own h->hw | out+xp (fire&forget) |
// poll flag(t+1) | recv | scatter partner h->hw | lgkm+barrier.
__global__ __launch_bounds__(512, 2) void rnn_k(
    const unsigned short* __restrict__ M, const float* __restrict__ xp,
    float* __restrict__ out, char* __restrict__ ws) {
  const int bid = blockIdx.x;
  if (bid & 4) return;
  const int g = bid & 3;
  const int role = bid >> 3;
  const int prole = 1 - role;
  const int tid = threadIdx.x;
  const int w = tid >> 6;      // 0..7
  const int lane = tid & 63;
  const int n = lane & 15;
  const int q = lane >> 4;     // 0..3
  const int colbase = role * 256 + w * 32;
  const int pcolbase = prole * 256 + w * 32;

  __shared__ __align__(16) unsigned short hb[2][16 * 512];
  __shared__ int sFast;

  {  // zero hb[0] (t=0 state): 16KB / 512 thr = 2 uint4
    uint4 z = {0, 0, 0, 0};
    uint4* p = (uint4*)&hb[0][0];
    p[tid] = z;
    p[tid + 512] = z;
  }

  unsigned* flags = (unsigned*)(ws + WS_FLAGS);
  unsigned* xcct = (unsigned*)(ws + WS_XCC);
  if (tid == 0) {
    unsigned myx;
    asm volatile("s_getreg_b32 %0, hwreg(HW_REG_XCC_ID)" : "=s"(myx));
    __hip_atomic_store(&xcct[bid], myx + 1, __ATOMIC_RELAXED, __HIP_MEMORY_SCOPE_AGENT);
    unsigned ox;
    while ((ox = __hip_atomic_load(&xcct[bid ^ 8], __ATOMIC_RELAXED,
                                   __HIP_MEMORY_SCOPE_AGENT)) == 0u)
      __builtin_amdgcn_s_sleep(2);
    sFast = (ox == myx + 1) ? 1 : 0;
  }

  const float C1 = (float)(1.0 - 16.67 / 100.0);

  // ---- load weights into physical AGPRs a0-a127 (once) ----
  {
    const unsigned short* mb0 = M + (colbase + 0 * 16 + n) * 512 + q * 8;
    const unsigned short* mb1 = M + (colbase + 1 * 16 + n) * 512 + q * 8;
#define WQ0(kt) (*(const u32x4*)(mb0 + (kt) * 32))
#define WQ1(kt) (*(const u32x4*)(mb1 + (kt) * 32))
    PINQ(WQ0(0),  "a0",   "a1",   "a2",   "a3");
    PINQ(WQ1(0),  "a4",   "a5",   "a6",   "a7");
    PINQ(WQ0(1),  "a8",   "a9",   "a10",  "a11");
    PINQ(WQ1(1),  "a12",  "a13",  "a14",  "a15");
    PINQ(WQ0(2),  "a16",  "a17",  "a18",  "a19");
    PINQ(WQ1(2),  "a20",  "a21",  "a22",  "a23");
    PINQ(WQ0(3),  "a24",  "a25",  "a26",  "a27");
    PINQ(WQ1(3),  "a28",  "a29",  "a30",  "a31");
    PINQ(WQ0(4),  "a32",  "a33",  "a34",  "a35");
    PINQ(WQ1(4),  "a36",  "a37",  "a38",  "a39");
    PINQ(WQ0(5),  "a40",  "a41",  "a42",  "a43");
    PINQ(WQ1(5),  "a44",  "a45",  "a46",  "a47");
    PINQ(WQ0(6),  "a48",  "a49",  "a50",  "a51");
    PINQ(WQ1(6),  "a52",  "a53",  "a54",  "a55");
    PINQ(WQ0(7),  "a56",  "a57",  "a58",  "a59");
    PINQ(WQ1(7),  "a60",  "a61",  "a62",  "a63");
    PINQ(WQ0(8),  "a64",  "a65",  "a66",  "a67");
    PINQ(WQ1(8),  "a68",  "a69",  "a70",  "a71");
    PINQ(WQ0(9),  "a72",  "a73",  "a74",  "a75");
    PINQ(WQ1(9),  "a76",  "a77",  "a78",  "a79");
    PINQ(WQ0(10), "a80",  "a81",  "a82",  "a83");
    PINQ(WQ1(10), "a84",  "a85",  "a86",  "a87");
    PINQ(WQ0(11), "a88",  "a89",  "a90",  "a91");
    PINQ(WQ1(11), "a92",  "a93",  "a94",  "a95");
    PINQ(WQ0(12), "a96",  "a97",  "a98",  "a99");
    PINQ(WQ1(12), "a100", "a101", "a102", "a103");
    PINQ(WQ0(13), "a104", "a105", "a106", "a107");
    PINQ(WQ1(13), "a108", "a109", "a110", "a111");
    PINQ(WQ0(14), "a112", "a113", "a114", "a115");
    PINQ(WQ1(14), "a116", "a117", "a118", "a119");
    PINQ(WQ0(15), "a120", "a121", "a122", "a123");
    PINQ(WQ1(15), "a124", "a125", "a126", "a127");
  }

  float hprev[2][4];
  #pragma unroll
  for (int a = 0; a < 2; a++)
    #pragma unroll
    for (int b = 0; b < 4; b++) hprev[a][b] = 0.f;

  const bool hasxp = (role == 0);
  const float* xpb = xp + ((g * 16 + 4 * q) << 8) + colbase + n;
  float xpA[2][4], xpB[2][4];
  #pragma unroll
  for (int a = 0; a < 2; a++)
    #pragma unroll
    for (int b = 0; b < 4; b++) { xpA[a][b] = 0.f; xpB[a][b] = 0.f; }
  if (hasxp) {
    #pragma unroll
    for (int nt = 0; nt < 2; nt++)
      #pragma unroll
      for (int j = 0; j < 4; j++) {
        xpA[nt][j] = __builtin_nontemporal_load(xpb + 0L * 16384 + j * 256 + nt * 16);
        xpB[nt][j] = __builtin_nontemporal_load(xpb + 1L * 16384 + j * 256 + nt * 16);
      }
  }

  float* outb = out + (long)(g * 16 + 4 * q) * (NT * NH) + colbase + n;

  // exchange addressing (payload blob is per-tid, 16B; 512 tid x 16B = 8KB/slot)
  char* Xb = ws + WS_X;
  char* xs0 = Xb + ((g * 2 + role) * 2 + 0) * 8192 + tid * 16;
  char* xs1 = Xb + ((g * 2 + role) * 2 + 1) * 8192 + tid * 16;
  const char* xr0 = Xb + ((g * 2 + prole) * 2 + 0) * 8192 + tid * 16;
  const char* xr1 = Xb + ((g * 2 + prole) * 2 + 1) * 8192 + tid * 16;
  unsigned* fs = flags + ((g * 2 + role) * 8 + w) * 16;
  unsigned* fr = flags + ((g * 2 + prole) * 8 + w) * 16;

  __syncthreads();
  const bool fastp = (sFast != 0);

  auto step = [&](unsigned short* hr, unsigned short* hw, int t,
                  float (&xpc)[2][4]) {
    short8 av[8];
    f32x4 acc[2];
    acc[0] = (f32x4){0.f, 0.f, 0.f, 0.f};
    acc[1] = (f32x4){0.f, 0.f, 0.f, 0.f};

    // ---- 1. fused MFMA over FULL K (hr holds complete h(t); read-only now)
    #pragma unroll
    for (int i = 0; i < 8; i++)
      av[i] = *(const short8*)(hr + ((unsigned)(n * 512 + i * 32 + q * 8) ^ SWZ(n)));
    KTGF(0, "a[0:3]",    "a[4:7]");
    KTG (1, "a[8:11]",   "a[12:15]");
    KTG (2, "a[16:19]",  "a[20:23]");
    KTG (3, "a[24:27]",  "a[28:31]");
    KTG (4, "a[32:35]",  "a[36:39]");
    KTG (5, "a[40:43]",  "a[44:47]");
    KTG (6, "a[48:51]",  "a[52:55]");
    KTG (7, "a[56:59]",  "a[60:63]");
    #pragma unroll
    for (int i = 0; i < 8; i++)
      av[i] = *(const short8*)(hr + ((unsigned)(n * 512 + (8 + i) * 32 + q * 8) ^ SWZ(n)));
    KTG (0, "a[64:67]",  "a[68:71]");
    KTG (1, "a[72:75]",  "a[76:79]");
    KTG (2, "a[80:83]",  "a[84:87]");
    KTG (3, "a[88:91]",  "a[92:95]");
    KTG (4, "a[96:99]",  "a[100:103]");
    KTG (5, "a[104:107]","a[108:111]");
    KTG (6, "a[112:115]","a[116:119]");
    KTGL(7, "a[120:123]","a[124:127]");

    // ---- 2. finalize f32 + cvt
    unsigned dw[4];
    #pragma unroll
    for (int nt = 0; nt < 2; nt++) {
      #pragma unroll
      for (int j = 0; j < 4; j++) {
        float v = fmaf(hprev[nt][j], C1, acc[nt][j] + xpc[nt][j]);
        v = fmaxf(v, 0.f);
        hprev[nt][j] = v;
      }
      asm("v_cvt_pk_bf16_f32 %0, %1, %2"
          : "=v"(dw[nt * 2]) : "v"(hprev[nt][0]), "v"(hprev[nt][1]));
      asm("v_cvt_pk_bf16_f32 %0, %1, %2"
          : "=v"(dw[nt * 2 + 1]) : "v"(hprev[nt][2]), "v"(hprev[nt][3]));
    }

    // ---- 3. ship h(t+1) FIRST (vmcnt(0) drains only this 16B store)
    {
      char* xb = ((t + 1) & 1) ? xs1 : xs0;
      if (fastp) {
        uint4 v0 = {dw[0], dw[1], dw[2], dw[3]};
        *(uint4*)xb = v0;
        asm volatile("s_waitcnt vmcnt(0)" ::: "memory");
        if (lane == 0) *(volatile unsigned*)fs = (unsigned)(t + 1);
      } else {
        #pragma unroll
        for (int i = 0; i < 2; i++) {
          ull u = (ull)dw[2 * i] | ((ull)dw[2 * i + 1] << 32);
          __hip_atomic_store((ull*)(xb + 8 * i), u, __ATOMIC_RELAXED,
                             __HIP_MEMORY_SCOPE_AGENT);
        }
        if (lane == 0)
          __hip_atomic_store(fs, (unsigned)(t + 1), __ATOMIC_RELEASE,
                             __HIP_MEMORY_SCOPE_AGENT);
      }
    }

    // ---- 4. own h(t+1) -> hw; then fire-and-forget out-stores + xp prefetch
    #pragma unroll
    for (int nt = 0; nt < 2; nt++) {
      #pragma unroll
      for (int jh = 0; jh < 2; jh++) {
        unsigned dv = dw[nt * 2 + jh];
        int r0 = 4 * q + 2 * jh, r1 = r0 + 1;
        int c = colbase + nt * 16 + n;
        hw[(unsigned)(r0 * 512 + c) ^ SWZ(r0)] = (unsigned short)dv;
        hw[(unsigned)(r1 * 512 + c) ^ SWZ(r1)] = (unsigned short)(dv >> 16);
      }
    }
    float* outt = outb + (long)t * NH;
    #pragma unroll
    for (int nt = 0; nt < 2; nt++)
      #pragma unroll
      for (int j = 0; j < 4; j++)
        __builtin_nontemporal_store(hprev[nt][j],
                                    outt + (long)j * (NT * NH) + nt * 16);
    if (hasxp) {
      int tn = t + 2; if (tn >= NT) tn = 0;  // wrap: values unused, stay valid
      const float* xpl = xpb + (long)tn * 16384;
      #pragma unroll
      for (int nt = 0; nt < 2; nt++)
        #pragma unroll
        for (int j = 0; j < 4; j++)
          xpc[nt][j] = __builtin_nontemporal_load(xpl + j * 256 + nt * 16);
    }

    // ---- 5. poll + recv partner h(t+1), scatter -> hw
    {
      unsigned pd[4];
      const char* xb = ((t + 1) & 1) ? xr1 : xr0;
      if (fastp) {
        while (*(volatile const unsigned*)fr < (unsigned)(t + 1))
          __builtin_amdgcn_s_sleep(1);
        volatile const unsigned* xv = (volatile const unsigned*)xb;
        #pragma unroll
        for (int i = 0; i < 4; i++) pd[i] = xv[i];
      } else {
        while (__hip_atomic_load(fr, __ATOMIC_RELAXED,
                                 __HIP_MEMORY_SCOPE_AGENT) < (unsigned)(t + 1))
          __builtin_amdgcn_s_sleep(1);
        #pragma unroll
        for (int i = 0; i < 2; i++) {
          ull u = __hip_atomic_load((const ull*)(xb + 8 * i), __ATOMIC_RELAXED,
                                    __HIP_MEMORY_SCOPE_AGENT);
          pd[2 * i] = (unsigned)u;
          pd[2 * i + 1] = (unsigned)(u >> 32);
        }
      }
      #pragma unroll
      for (int nt = 0; nt < 2; nt++) {
        #pragma unroll
        for (int jh = 0; jh < 2; jh++) {
          unsigned dv = pd[nt * 2 + jh];
          int r0 = 4 * q + 2 * jh, r1 = r0 + 1;
          int c = pcolbase + nt * 16 + n;
          hw[(unsigned)(r0 * 512 + c) ^ SWZ(r0)] = (unsigned short)dv;
          hw[(unsigned)(r1 * 512 + c) ^ SWZ(r1)] = (unsigned short)(dv >> 16);
        }
      }
    }
    // ---- 6. the ONLY barrier: hw complete before next step reads it
    asm volatile("s_waitcnt lgkmcnt(0)\n\ts_barrier" ::: "memory");
  };

  #pragma unroll 1
  for (int t = 0; t < NT; t += 2) {
    step(hb[0], hb[1], t, xpA);
    step(hb[1], hb[0], t + 1, xpB);
  }

  // final h1, h2
  const long fbase = (long)NB * NT * NH;  // 33554432
  #pragma unroll
  for (int nt = 0; nt < 2; nt++) {
    #pragma unroll
    for (int j = 0; j < 4; j++) {
      int b = g * 16 + 4 * q + j;
      int col = colbase + nt * 16 + n;
      long off = (col < 256) ? (fbase + b * 256 + col)
                             : (fbase + 16384 + b * 256 + (col - 256));
      out[off] = hprev[nt][j];
    }
  }
}

extern "C" void kernel_launch(void* const* d_in, const int* in_sizes, int n_in,
                              void* d_out, int out_size, void* d_ws, size_t ws_size,
                              hipStream_t stream) {
  const float* x   = (const float*)d_in[0];
  const float* Wi  = (const float*)d_in[2];
  const float* bi  = (const float*)d_in[3];
  const float* W11 = (const float*)d_in[4];
  const float* W22 = (const float*)d_in[5];
  const float* W12 = (const float*)d_in[6];
  const float* W21 = (const float*)d_in[7];
  float* out = (float*)d_out;

  unsigned short* M = (unsigned short*)d_ws;
  float* WiT = (float*)((char*)d_ws + 524288);
  unsigned* ctrl = (unsigned*)((char*)d_ws + WS_FLAGS);
  float* xp = (float*)((char*)d_ws + WS_XP);

  buildM_k<<<1024, 256, 0, stream>>>(W11, W22, W12, W21, M, ctrl);
  buildWiT_k<<<128, 256, 0, stream>>>(Wi, WiT);
  xproj_k<<<1024, 256, 0, stream>>>(x, WiT, bi, xp);
  rnn_k<<<16, 512, 0, stream>>>(M, xp, out, (char*)d_ws);
}